// Round 10
// baseline (348.805 us; speedup 1.0000x reference)
//
#include <hip/hip_runtime.h>
#include <hip/hip_bf16.h>
#include <cmath>
#include <cstdint>
#include <cstddef>

// Problem constants: B=4, C=256, H=W=256, DS=4 -> h=w=64, N=4096, Cq=16
typedef unsigned short u16;
typedef __attribute__((ext_vector_type(8))) __bf16 bf16x8;
typedef __attribute__((ext_vector_type(4))) float f32x4;
typedef __attribute__((ext_vector_type(8))) unsigned short us8;
typedef __attribute__((ext_vector_type(4))) unsigned short us4;

// Workspace layout (bytes)
static const size_t OFF_ODS   = 0;            // [B][C][4096] fp32: xd first, then out_ds (aliased)
static const size_t OFF_QT    = 16777216;     // [B][4096][16] fp32, 1 MB
static const size_t OFF_KT    = 17825792;     // [B][4096][16] fp32, 1 MB
static const size_t OFF_VT    = 18874368;     // [B][256][4096] bf16 (V transposed), 8 MB
static const size_t OFF_SPART = 27262976;     // [1024 blocks][32] fp32 partial col-sums, 128 KB
static const size_t OFF_MEAN  = 27394048;     // 1 float
static const size_t OFF_WVT   = 27395072;     // WvT [256][256] fp32, 256 KB

__device__ __forceinline__ void gl2lds16(const void* gsrc, void* ldst) {
  __builtin_amdgcn_global_load_lds(
      (const __attribute__((address_space(1))) unsigned int*)gsrc,
      (__attribute__((address_space(3))) unsigned int*)ldst, 16, 0, 0);
}

// ---------------- Wv transpose (256x256) ----------------
// 16 blocks x 256 threads; each block transposes one 64x64 tile = 1024 float4 slots.
__global__ __launch_bounds__(256) void k_prep(const float* __restrict__ Wv,
                                              float* __restrict__ WvT) {
  __shared__ float t[64][68];
  const int rt = blockIdx.x >> 2, ct = blockIdx.x & 3;
  const int tid = threadIdx.x;
#pragma unroll
  for (int i = 0; i < 4; ++i) {
    int u = tid + i * 256;               // 0..1023
    int r = u >> 4, c4 = u & 15;
    *reinterpret_cast<float4*>(&t[r][c4 * 4]) =
        *reinterpret_cast<const float4*>(&Wv[(size_t)(rt * 64 + r) * 256u + ct * 64 + c4 * 4]);
  }
  __syncthreads();
#pragma unroll
  for (int i = 0; i < 4; ++i) {
    int u = tid + i * 256;               // 0..1023
    int c = u >> 4, r4 = u & 15;
    // FIX: gather COLUMN c of the staged tile (true transpose):
    // WvT[ct*64+c][rt*64+r4*4+j] = t[r4*4+j][c] = Wv[rt*64+r4*4+j][ct*64+c]
    float4 v = make_float4(t[r4 * 4 + 0][c], t[r4 * 4 + 1][c],
                           t[r4 * 4 + 2][c], t[r4 * 4 + 3][c]);
    *reinterpret_cast<float4*>(&WvT[(size_t)(ct * 64 + c) * 256u + rt * 64 + r4 * 4]) = v;
  }
}

// ---------------- maxpool 4x4 (streaming, 16384 blocks) ----------------
__global__ __launch_bounds__(256) void k_pool(const float* __restrict__ x,
                                              float* __restrict__ xd) {
  unsigned idx = blockIdx.x * 256u + threadIdx.x;      // < 4*256*64*64
  unsigned xo = idx & 63u;
  unsigned yo = (idx >> 6) & 63u;
  unsigned bc = idx >> 12;                             // b*256 + c
  const float* base = x + (size_t)bc * 65536u + yo * 1024u + xo * 4u;
  float m = -1e30f;
#pragma unroll
  for (int dy = 0; dy < 4; ++dy) {
    float4 v = *reinterpret_cast<const float4*>(base + dy * 256);
    m = fmaxf(m, fmaxf(fmaxf(v.x, v.y), fmaxf(v.z, v.w)));
  }
  xd[(size_t)bc * 4096u + yo * 64u + xo] = m;
}

// ---------------- q/k/v 1x1 convs + column sums ----------------
// 1024 blocks (b x 256 strips of 16 tokens), 256 threads, 53.8 KB LDS -> 3 blocks/CU.
__global__ __launch_bounds__(256) void k_qkv(const float* __restrict__ xd,
                                             const float* __restrict__ WvT, const float* __restrict__ bv,
                                             const float* __restrict__ Wq, const float* __restrict__ bq,
                                             const float* __restrict__ Wk, const float* __restrict__ bk,
                                             float* __restrict__ qT, float* __restrict__ kT,
                                             u16* __restrict__ vT, float* __restrict__ Spart) {
  __shared__ float xs[256][20];     // 20480 B (rows 80 B, 16B-aligned)
  __shared__ float wqk[32][260];    // 33280 B (rows 1040 B, 16B-aligned)
  const int blk = blockIdx.x;
  const int b = blk >> 8, n0 = (blk & 255) * 16;
  const int tid = threadIdx.x;

  // ---- stage xs (256c x 16 tok) and wqk (32 rows x 256) ----
  {
    const float* src = xd + (size_t)b * 1048576u + n0;
#pragma unroll
    for (int i = 0; i < 4; ++i) {
      int slot = tid + i * 256;          // 0..1023 float4 slots
      int c = slot >> 2, qq = slot & 3;
      *reinterpret_cast<float4*>(&xs[c][qq * 4]) =
          *reinterpret_cast<const float4*>(src + (size_t)c * 4096u + qq * 4);
    }
#pragma unroll
    for (int i = 0; i < 8; ++i) {
      int slot = tid + i * 256;          // 0..2047 float4 slots
      int o = slot >> 6, c4 = slot & 63;
      const float* srcw = (o < 16) ? (Wq + (size_t)o * 256u) : (Wk + (size_t)(o - 16) * 256u);
      *reinterpret_cast<float4*>(&wqk[o][c4 * 4]) =
          *reinterpret_cast<const float4*>(srcw + c4 * 4);
    }
  }
  __syncthreads();

  // ---- v conv: thread = (cp = tid>>1 -> couts 2cp,2cp+1; th = tid&1 -> tokens th*8..+8) ----
  {
    const int cp = tid >> 1, th = tid & 1;
    float acc0[8], acc1[8];
#pragma unroll
    for (int j = 0; j < 8; ++j) { acc0[j] = 0.f; acc1[j] = 0.f; }
    const float* wt = WvT + 2 * cp;
    for (int cin = 0; cin < 256; ++cin) {
      float2 w2 = *reinterpret_cast<const float2*>(wt + (size_t)cin * 256u);
      float4 xa = *reinterpret_cast<const float4*>(&xs[cin][th * 8]);
      float4 xb = *reinterpret_cast<const float4*>(&xs[cin][th * 8 + 4]);
      acc0[0] = fmaf(w2.x, xa.x, acc0[0]); acc1[0] = fmaf(w2.y, xa.x, acc1[0]);
      acc0[1] = fmaf(w2.x, xa.y, acc0[1]); acc1[1] = fmaf(w2.y, xa.y, acc1[1]);
      acc0[2] = fmaf(w2.x, xa.z, acc0[2]); acc1[2] = fmaf(w2.y, xa.z, acc1[2]);
      acc0[3] = fmaf(w2.x, xa.w, acc0[3]); acc1[3] = fmaf(w2.y, xa.w, acc1[3]);
      acc0[4] = fmaf(w2.x, xb.x, acc0[4]); acc1[4] = fmaf(w2.y, xb.x, acc1[4]);
      acc0[5] = fmaf(w2.x, xb.y, acc0[5]); acc1[5] = fmaf(w2.y, xb.y, acc1[5]);
      acc0[6] = fmaf(w2.x, xb.z, acc0[6]); acc1[6] = fmaf(w2.y, xb.z, acc1[6]);
      acc0[7] = fmaf(w2.x, xb.w, acc0[7]); acc1[7] = fmaf(w2.y, xb.w, acc1[7]);
    }
    float b0 = bv[2 * cp], b1 = bv[2 * cp + 1];
    us8 o0, o1;
#pragma unroll
    for (int j = 0; j < 8; ++j) {
      o0[j] = __builtin_bit_cast(u16, __float2bfloat16(acc0[j] + b0));
      o1[j] = __builtin_bit_cast(u16, __float2bfloat16(acc1[j] + b1));
    }
    *reinterpret_cast<us8*>(vT + ((size_t)b * 256u + 2 * cp)     * 4096u + n0 + th * 8) = o0;
    *reinterpret_cast<us8*>(vT + ((size_t)b * 256u + 2 * cp + 1) * 4096u + n0 + th * 8) = o1;
  }

  // ---- q/k: thread = (o = tid>>3 in 0..31, t8 = tid&7 -> tokens t8, t8+8) ----
  {
    const int o = tid >> 3, t8 = tid & 7;
    float a0 = 0.f, a1 = 0.f;
    for (int cin = 0; cin < 256; ++cin) {
      float w = wqk[o][cin];
      a0 = fmaf(w, xs[cin][t8], a0);
      a1 = fmaf(w, xs[cin][t8 + 8], a1);
    }
    if (o < 16) {
      float bb = bq[o];
      qT[((size_t)b * 4096u + n0 + t8)     * 16u + o] = a0 + bb;
      qT[((size_t)b * 4096u + n0 + t8 + 8) * 16u + o] = a1 + bb;
    } else {
      float bb = bk[o - 16];
      kT[((size_t)b * 4096u + n0 + t8)     * 16u + (o - 16)] = a0 + bb;
      kT[((size_t)b * 4096u + n0 + t8 + 8) * 16u + (o - 16)] = a1 + bb;
    }
    // per-block column sums (bias added in k_mean)
    float s = a0 + a1;
    s += __shfl_xor(s, 1); s += __shfl_xor(s, 2); s += __shfl_xor(s, 4);
    if (t8 == 0) Spart[(size_t)blk * 32u + o] = s;
  }
}

// ---------------- scalar mean of att from block partial sums ----------------
__global__ __launch_bounds__(64) void k_mean(const float* __restrict__ Spart,
                                             const float* __restrict__ bq, const float* __restrict__ bk,
                                             float* __restrict__ meanp) {
  int t = threadIdx.x;        // (b,o): b = t>>4, o = t&15
  int b = t >> 4, o = t & 15;
  float sq = 4096.0f * bq[o], sk = 4096.0f * bk[o];
  for (int blk = 0; blk < 256; ++blk) {
    const float* p = Spart + ((size_t)(b * 256 + blk)) * 32u;
    sq += p[o];
    sk += p[16 + o];
  }
  float pr = sq * sk;
#pragma unroll
  for (int off = 32; off > 0; off >>= 1) pr += __shfl_down(pr, off);
  if (t == 0) *meanp = pr * (1.0f / 67108864.0f);   // / (B*N*N)
}

// ---------------- one-pass MFMA flash: split-bf16 QK^T + masked softmax + PV ----------------
// 256 blocks, XCD-bijective remap: batch = bits1-2 of blockIdx -> each XCD serves ONE batch
// (2 MB V + 256 KB K fit its 4 MB L2). 512 threads = 8 waves (2/SIMD).
__global__ __launch_bounds__(512) void k_flash(const float* __restrict__ qT,
                                               const float* __restrict__ kT,
                                               const u16* __restrict__ vT,
                                               const float* __restrict__ meanp,
                                               float* __restrict__ ods) {
  __shared__ u16 vbuf[2][16384];       // [buf][c row(256) x kv(64)] linear, source-swizzled (64 KB)
  __shared__ u16 kfh[2][4][64][8];     // B-frag [k_hi|k_hi], fragment-linear (8 KB)
  __shared__ u16 kfl[2][4][64][8];     // B-frag [k_lo|k_lo] (8 KB)
  __shared__ u16 pfr[8][2][64][8];     // per-wave P A-frags (16 KB)

  const int orig = blockIdx.x;
  const int b    = (orig >> 1) & 3;                        // bits1-2 -> XCD pair per batch
  const int row0 = (((orig & 1) << 5) | (orig >> 3)) * 64; // bijective q-tile remap
  const int tid  = threadIdx.x;
  const int w    = tid >> 6;
  const int lane = tid & 63;
  const int wq   = w & 3;
  const int wc   = w >> 2;
  const int g    = lane >> 4;          // 0..3
  const int c16  = lane & 15;

  const float mean = *meanp;

  // ---- Q A-frags (split bf16: A1=[q_hi|q_lo], A2=[q_hi|0]) ----
  float qv[16];
  {
    const float* qrow = qT + ((size_t)b*4096 + row0 + 16*wq + c16) * 16;
#pragma unroll
    for (int i = 0; i < 4; ++i) {
      float4 t4 = reinterpret_cast<const float4*>(qrow)[i];
      qv[4*i] = t4.x; qv[4*i+1] = t4.y; qv[4*i+2] = t4.z; qv[4*i+3] = t4.w;
    }
  }
  u16 qhi[16], qlo[16];
#pragma unroll
  for (int i = 0; i < 16; ++i) {
    __hip_bfloat16 h = __float2bfloat16(qv[i]);
    float fh = __bfloat162float(h);
    __hip_bfloat16 lo = __float2bfloat16(qv[i] - fh);
    qhi[i] = __builtin_bit_cast(u16, h);
    qlo[i] = __builtin_bit_cast(u16, lo);
  }
  us8 a1u, a2u;
  {
    const bool koff8  = (g & 1);
    const bool lo_src = (g >= 2);
#pragma unroll
    for (int i = 0; i < 8; ++i) {
      u16 hs = koff8 ? qhi[i+8] : qhi[i];
      u16 ls = koff8 ? qlo[i+8] : qlo[i];
      a1u[i] = lo_src ? ls : hs;
      a2u[i] = lo_src ? (u16)0 : hs;
    }
  }
  const bf16x8 A1 = __builtin_bit_cast(bf16x8, a1u);
  const bf16x8 A2 = __builtin_bit_cast(bf16x8, a2u);

  f32x4 O[8];
#pragma unroll
  for (int i = 0; i < 8; ++i) O[i] = (f32x4){0.f, 0.f, 0.f, 0.f};
  float Lr[4] = {0.f, 0.f, 0.f, 0.f};
  float M = 0.0f;

  // K staging params (threads 0..255 only)
  const int kv_s = tid >> 2, t4v = tid & 3;
  const int ks = kv_s >> 4, kld0 = (kv_s & 15) + 16*(t4v >> 1), ki0 = 4*(t4v & 1);

  // ---- prologue: stage tile 0 ----
  {
    const u16* vsrc = vT + (size_t)b*256*4096;
#pragma unroll
    for (int i = 0; i < 4; ++i) {
      int u = i*512 + tid;
      int row = u >> 3, slot = u & 7;
      int sb = (slot*16) ^ ((row & 7) << 4);
      gl2lds16((const char*)(vsrc + (size_t)row*4096) + sb, (char*)&vbuf[0][0] + u*16);
    }
    if (tid < 256) {
      float4 kvec = *reinterpret_cast<const float4*>(kT + ((size_t)b*4096 + kv_s)*16 + 4*t4v);
      float kf[4] = {kvec.x, kvec.y, kvec.z, kvec.w};
      us4 h4, l4;
#pragma unroll
      for (int di = 0; di < 4; ++di) {
        __hip_bfloat16 h = __float2bfloat16(kf[di]);
        float fh = __bfloat162float(h);
        __hip_bfloat16 lo = __float2bfloat16(kf[di] - fh);
        h4[di] = __builtin_bit_cast(u16, h);
        l4[di] = __builtin_bit_cast(u16, lo);
      }
      *reinterpret_cast<us4*>(&kfh[0][ks][kld0][ki0])    = h4;
      *reinterpret_cast<us4*>(&kfh[0][ks][kld0+32][ki0]) = h4;
      *reinterpret_cast<us4*>(&kfl[0][ks][kld0][ki0])    = l4;
      *reinterpret_cast<us4*>(&kfl[0][ks][kld0+32][ki0]) = l4;
    }
  }
  __syncthreads();

  // ---- main loop over 64 KV tiles of 64 ----
  for (int t = 0; t < 64; ++t) {
    const int cur = t & 1, nxt = cur ^ 1;
    const int kv0n = ((t + 1) & 63) * 64;

    // [D] issue next-tile staging (K -> regs, V -> LDS via DMA)
    float4 kvec;
    if (tid < 256)
      kvec = *reinterpret_cast<const float4*>(kT + ((size_t)b*4096 + kv0n + kv_s)*16 + 4*t4v);
    {
      const u16* vsrc = vT + (size_t)b*256*4096 + kv0n;
#pragma unroll
      for (int i = 0; i < 4; ++i) {
        int u = i*512 + tid;
        int row = u >> 3, slot = u & 7;
        int sb = (slot*16) ^ ((row & 7) << 4);
        gl2lds16((const char*)(vsrc + (size_t)row*4096) + sb, (char*)&vbuf[nxt][0] + u*16);
      }
    }

    // [A] scores: 4 kv-subtiles x 2 MFMA (split-bf16)
    f32x4 S[4];
#pragma unroll
    for (int s = 0; s < 4; ++s) {
      bf16x8 bh = __builtin_bit_cast(bf16x8, *reinterpret_cast<const us8*>(&kfh[cur][s][lane][0]));
      bf16x8 bl = __builtin_bit_cast(bf16x8, *reinterpret_cast<const us8*>(&kfl[cur][s][lane][0]));
      f32x4 acc = (f32x4){0.f, 0.f, 0.f, 0.f};
      acc = __builtin_amdgcn_mfma_f32_16x16x32_bf16(A1, bh, acc, 0, 0, 0);
      acc = __builtin_amdgcn_mfma_f32_16x16x32_bf16(A2, bl, acc, 0, 0, 0);
      S[s] = acc;
    }

    // [B] mask + deferred-max online softmax (wave-wide M, THR=8)
    float pmax = -1e30f;
#pragma unroll
    for (int s = 0; s < 4; ++s)
#pragma unroll
      for (int r = 0; r < 4; ++r) {
        float v = S[s][r];
        v = (v < mean) ? 0.f : v;
        S[s][r] = v;
        pmax = fmaxf(pmax, v);
      }
    if (!__all(pmax <= M + 8.0f)) {
      float mw = pmax;
#pragma unroll
      for (int off = 1; off < 64; off <<= 1) mw = fmaxf(mw, __shfl_xor(mw, off));
      float Mn = fmaxf(M, mw);
      float sc = __expf(M - Mn);
#pragma unroll
      for (int i = 0; i < 8; ++i) {
        O[i][0] *= sc; O[i][1] *= sc; O[i][2] *= sc; O[i][3] *= sc;
      }
#pragma unroll
      for (int r = 0; r < 4; ++r) Lr[r] *= sc;
      M = Mn;
    }
    u16 pb[4][4];
#pragma unroll
    for (int s = 0; s < 4; ++s)
#pragma unroll
      for (int r = 0; r < 4; ++r) {
        float p = __expf(S[s][r] - M);
        Lr[r] += p;
        pb[s][r] = __builtin_bit_cast(u16, __float2bfloat16(p));
      }

    // [C] write P into per-wave A-frag copy
    {
      const int ib = lane & 7;
      const int t1 = (lane >> 3) & 1;
#pragma unroll
      for (int s = 0; s < 4; ++s) {
        const int c2 = s >> 1;
        const int ldb = 16 * ((2*s + t1) & 3) + 4*g;
#pragma unroll
        for (int r = 0; r < 4; ++r) pfr[w][c2][ldb + r][ib] = pb[s][r];
      }
    }
    asm volatile("s_waitcnt lgkmcnt(0)" ::: "memory");
    __builtin_amdgcn_sched_barrier(0);

    // [G] PV: 2 k-chunks x 8 c-subtiles (this wave's c-half)
#pragma unroll
    for (int c2 = 0; c2 < 2; ++c2) {
      bf16x8 pa = __builtin_bit_cast(bf16x8, *reinterpret_cast<const us8*>(&pfr[w][c2][lane][0]));
#pragma unroll
      for (int ct = 0; ct < 8; ++ct) {
        int row = (wc*8 + ct)*16 + c16;
        int off = (c2*64 + g*16) ^ ((lane & 7) << 4);
        bf16x8 vb = __builtin_bit_cast(bf16x8,
            *reinterpret_cast<const us8*>((const char*)&vbuf[cur][0] + row*128 + off));
        O[ct] = __builtin_amdgcn_mfma_f32_16x16x32_bf16(pa, vb, O[ct], 0, 0, 0);
      }
    }

    // [H] convert + write K frags for next tile
    if (tid < 256) {
      float kf[4] = {kvec.x, kvec.y, kvec.z, kvec.w};
      us4 h4, l4;
#pragma unroll
      for (int di = 0; di < 4; ++di) {
        __hip_bfloat16 h = __float2bfloat16(kf[di]);
        float fh = __bfloat162float(h);
        __hip_bfloat16 lo = __float2bfloat16(kf[di] - fh);
        h4[di] = __builtin_bit_cast(u16, h);
        l4[di] = __builtin_bit_cast(u16, lo);
      }
      *reinterpret_cast<us4*>(&kfh[nxt][ks][kld0][ki0])    = h4;
      *reinterpret_cast<us4*>(&kfh[nxt][ks][kld0+32][ki0]) = h4;
      *reinterpret_cast<us4*>(&kfl[nxt][ks][kld0][ki0])    = l4;
      *reinterpret_cast<us4*>(&kfl[nxt][ks][kld0+32][ki0]) = l4;
    }

    __syncthreads();
  }

  // ---- epilogue: reduce L across the 16 kv-lanes, write O/L to ods [b][c][n] ----
#pragma unroll
  for (int r = 0; r < 4; ++r) {
    float v = Lr[r];
#pragma unroll
    for (int off = 1; off < 16; off <<= 1) v += __shfl_xor(v, off);
    Lr[r] = v;
  }
  float inv[4];
#pragma unroll
  for (int r = 0; r < 4; ++r) inv[r] = 1.0f / Lr[r];
#pragma unroll
  for (int ct = 0; ct < 8; ++ct) {
    int c = (wc*8 + ct)*16 + c16;
    float* dst = ods + ((size_t)b*256 + c) * 4096u + row0 + 16*wq + 4*g;
    float4 o4 = make_float4(O[ct][0]*inv[0], O[ct][1]*inv[1], O[ct][2]*inv[2], O[ct][3]*inv[3]);
    *reinterpret_cast<float4*>(dst) = o4;
  }
}

// ---------------- bilinear 4x upsample + residual, 4 px/thread ----------------
__global__ __launch_bounds__(256) void k_up(const float* __restrict__ ods, const float* __restrict__ x,
                                            float* __restrict__ out) {
  unsigned idx4 = blockIdx.x * 256u + threadIdx.x;   // < 16777216
  int a  = (int)(idx4 & 63u);          // horizontal cell = output j strip [4a,4a+4)
  int i  = (int)((idx4 >> 6) & 255u);  // output row
  size_t bc = idx4 >> 14;              // b*256 + c

  float py = (i + 0.5f) * 0.25f - 0.5f;
  float y0f = floorf(py);
  float wy = py - y0f;
  int y0 = (int)y0f, y1 = y0 + 1;
  y0 = max(y0, 0); y1 = min(y1, 63);

  int xm1 = max(a - 1, 0), xp1 = min(a + 1, 63);

  const float* r0 = ods + bc * 4096u + y0 * 64;
  const float* r1 = ods + bc * 4096u + y1 * 64;
  float wy1 = 1.f - wy;
  float vm1 = wy1 * r0[xm1] + wy * r1[xm1];
  float v0  = wy1 * r0[a]   + wy * r1[a];
  float vp1 = wy1 * r0[xp1] + wy * r1[xp1];

  float4 xv = *reinterpret_cast<const float4*>(x + (size_t)idx4 * 4u);
  float4 o4;
  o4.x = fmaf(0.375f, vm1, 0.625f * v0) + xv.x;
  o4.y = fmaf(0.125f, vm1, 0.875f * v0) + xv.y;
  o4.z = fmaf(0.875f, v0, 0.125f * vp1) + xv.z;
  o4.w = fmaf(0.625f, v0, 0.375f * vp1) + xv.w;
  *reinterpret_cast<float4*>(out + (size_t)idx4 * 4u) = o4;
}

extern "C" void kernel_launch(void* const* d_in, const int* in_sizes, int n_in,
                              void* d_out, int out_size, void* d_ws, size_t ws_size,
                              hipStream_t stream) {
  const float* x  = (const float*)d_in[0];
  const float* Wq = (const float*)d_in[1];
  const float* bq = (const float*)d_in[2];
  const float* Wk = (const float*)d_in[3];
  const float* bk = (const float*)d_in[4];
  const float* Wv = (const float*)d_in[5];
  const float* bv = (const float*)d_in[6];
  float* out = (float*)d_out;

  char* ws = (char*)d_ws;
  float* xd    = (float*)(ws + OFF_ODS);   // xd first, ods later (aliased; xd dead after k_qkv)
  float* qT    = (float*)(ws + OFF_QT);
  float* kT    = (float*)(ws + OFF_KT);
  u16*   vT    = (u16*)(ws + OFF_VT);
  float* Spart = (float*)(ws + OFF_SPART);
  float* mnp   = (float*)(ws + OFF_MEAN);
  float* WvT   = (float*)(ws + OFF_WVT);
  float* ods   = xd;

  k_prep<<<dim3(16), dim3(256), 0, stream>>>(Wv, WvT);
  k_pool<<<dim3(16384), dim3(256), 0, stream>>>(x, xd);
  k_qkv<<<dim3(1024), dim3(256), 0, stream>>>(xd, WvT, bv, Wq, bq, Wk, bk, qT, kT, vT, Spart);
  k_mean<<<dim3(1), dim3(64), 0, stream>>>(Spart, bq, bk, mnp);
  k_flash<<<dim3(256), dim3(512), 0, stream>>>(qT, kT, vT, mnp, ods);
  k_up<<<dim3(65536), dim3(256), 0, stream>>>(ods, x, out);
}

// Round 11
// 320.364 us; speedup vs baseline: 1.0888x; 1.0888x over previous
//
#include <hip/hip_runtime.h>
#include <hip/hip_bf16.h>
#include <cmath>
#include <cstdint>
#include <cstddef>

// Problem constants: B=4, C=256, H=W=256, DS=4 -> h=w=64, N=4096, Cq=16
typedef unsigned short u16;
typedef __attribute__((ext_vector_type(8))) __bf16 bf16x8;
typedef __attribute__((ext_vector_type(4))) float f32x4;
typedef __attribute__((ext_vector_type(8))) unsigned short us8;
typedef __attribute__((ext_vector_type(4))) unsigned short us4;

// Workspace layout (bytes)
static const size_t OFF_ODS   = 0;            // [B][C][4096] fp32 out_ds (flash output), 16 MB
static const size_t OFF_QT    = 16777216;     // [B][4096][16] fp32, 1 MB
static const size_t OFF_KT    = 17825792;     // [B][4096][16] fp32, 1 MB
static const size_t OFF_VT    = 18874368;     // [B][256][4096] bf16 (V transposed), 8 MB
static const size_t OFF_SPART = 27262976;     // [512 blocks][32] fp32 partial col-sums, 64 KB
static const size_t OFF_MEAN  = 27394048;     // 1 float
static const size_t OFF_WVT   = 27395072;     // WvT [256][256] fp32, 256 KB

__device__ __forceinline__ void gl2lds16(const void* gsrc, void* ldst) {
  __builtin_amdgcn_global_load_lds(
      (const __attribute__((address_space(1))) unsigned int*)gsrc,
      (__attribute__((address_space(3))) unsigned int*)ldst, 16, 0, 0);
}

__device__ __forceinline__ float hmax4(float4 v) {
  return fmaxf(fmaxf(v.x, v.y), fmaxf(v.z, v.w));
}

// ---------------- Wv transpose (256x256) ----------------
__global__ __launch_bounds__(256) void k_prep(const float* __restrict__ Wv,
                                              float* __restrict__ WvT) {
  __shared__ float t[64][68];
  const int rt = blockIdx.x >> 2, ct = blockIdx.x & 3;
  const int tid = threadIdx.x;
#pragma unroll
  for (int i = 0; i < 4; ++i) {
    int u = tid + i * 256;               // 0..1023
    int r = u >> 4, c4 = u & 15;
    *reinterpret_cast<float4*>(&t[r][c4 * 4]) =
        *reinterpret_cast<const float4*>(&Wv[(size_t)(rt * 64 + r) * 256u + ct * 64 + c4 * 4]);
  }
  __syncthreads();
#pragma unroll
  for (int i = 0; i < 4; ++i) {
    int u = tid + i * 256;               // 0..1023
    int c = u >> 4, r4 = u & 15;
    float4 v = make_float4(t[r4 * 4 + 0][c], t[r4 * 4 + 1][c],
                           t[r4 * 4 + 2][c], t[r4 * 4 + 3][c]);
    *reinterpret_cast<float4*>(&WvT[(size_t)(ct * 64 + c) * 256u + rt * 64 + r4 * 4]) = v;
  }
}

// ---------------- fused maxpool + q/k/v convs + column sums ----------------
// 512 blocks = b(4) x yo(64) x half(2); 256 threads; LDS 36.9 KB -> 4 blocks/CU.
// Block handles 32 tokens (pooled row yo, cols hf*32..+32). x read exactly once; no xd.
__global__ __launch_bounds__(256) void k_front(const float* __restrict__ x,
                                               const float* __restrict__ WvT, const float* __restrict__ bv,
                                               const float* __restrict__ Wq, const float* __restrict__ bq,
                                               const float* __restrict__ Wk, const float* __restrict__ bk,
                                               float* __restrict__ qT, float* __restrict__ kT,
                                               u16* __restrict__ vT, float* __restrict__ Spart) {
  __shared__ float xs[256][36];     // 36864 B; row = 144 B (16B-aligned)
  const int blk = blockIdx.x;
  const int b = blk >> 7, yo = (blk >> 1) & 63, hf = blk & 1;
  const int n0 = yo * 64 + hf * 32;
  const int tid = threadIdx.x;

  // ---- pool: 8192 slots = (c, j4); wave-coalesced (consecutive lanes -> consecutive 16B) ----
  {
    const float* base = x + (size_t)b * 16777216u + (size_t)(4 * yo) * 256u + hf * 128;
#pragma unroll
    for (int i = 0; i < 32; ++i) {
      int slot = i * 256 + tid;          // 0..8191
      int c = slot >> 5, j4 = slot & 31; // j4 = pooled token within strip
      const float* p = base + (size_t)c * 65536u + j4 * 4;
      float4 r0 = *reinterpret_cast<const float4*>(p);
      float4 r1 = *reinterpret_cast<const float4*>(p + 256);
      float4 r2 = *reinterpret_cast<const float4*>(p + 512);
      float4 r3 = *reinterpret_cast<const float4*>(p + 768);
      xs[c][j4] = fmaxf(fmaxf(hmax4(r0), hmax4(r1)), fmaxf(hmax4(r2), hmax4(r3)));
    }
  }
  __syncthreads();

  // ---- v conv: thread = out-channel tid, 32-token register tile, WvT coalesced ----
  {
    float acc[32];
#pragma unroll
    for (int i = 0; i < 32; ++i) acc[i] = 0.f;
    for (int k = 0; k < 256; ++k) {
      float w = WvT[(size_t)k * 256u + tid];
#pragma unroll
      for (int j4 = 0; j4 < 8; ++j4) {
        float4 xv = *reinterpret_cast<const float4*>(&xs[k][j4 * 4]);
        acc[j4 * 4 + 0] = fmaf(w, xv.x, acc[j4 * 4 + 0]);
        acc[j4 * 4 + 1] = fmaf(w, xv.y, acc[j4 * 4 + 1]);
        acc[j4 * 4 + 2] = fmaf(w, xv.z, acc[j4 * 4 + 2]);
        acc[j4 * 4 + 3] = fmaf(w, xv.w, acc[j4 * 4 + 3]);
      }
    }
    float bb = bv[tid];
    u16* dst = vT + ((size_t)b * 256u + tid) * 4096u + n0;
#pragma unroll
    for (int q8 = 0; q8 < 4; ++q8) {
      us8 o8;
#pragma unroll
      for (int j = 0; j < 8; ++j)
        o8[j] = __builtin_bit_cast(u16, __float2bfloat16(acc[q8 * 8 + j] + bb));
      *reinterpret_cast<us8*>(dst + q8 * 8) = o8;
    }
  }

  // ---- q/k: thread = (o = tid>>3 in 0..31, t8 = tid&7 -> tokens t8*4..+4) ----
  {
    const int o = tid >> 3, t8 = tid & 7;
    const float* wrow = (o < 16) ? (Wq + (size_t)o * 256u) : (Wk + (size_t)(o - 16) * 256u);
    float a0 = 0.f, a1 = 0.f, a2 = 0.f, a3 = 0.f;
    for (int k = 0; k < 256; ++k) {
      float w = wrow[k];
      float4 xv = *reinterpret_cast<const float4*>(&xs[k][t8 * 4]);
      a0 = fmaf(w, xv.x, a0);
      a1 = fmaf(w, xv.y, a1);
      a2 = fmaf(w, xv.z, a2);
      a3 = fmaf(w, xv.w, a3);
    }
    float* dst = (o < 16) ? qT : kT;
    int oo = (o < 16) ? o : (o - 16);
    float bb = (o < 16) ? bq[oo] : bk[oo];
    size_t base = ((size_t)b * 4096u + n0 + t8 * 4) * 16u + oo;
    dst[base]       = a0 + bb;
    dst[base + 16]  = a1 + bb;
    dst[base + 32]  = a2 + bb;
    dst[base + 48]  = a3 + bb;
    // per-block column sums (bias added in k_mean)
    float s = a0 + a1 + a2 + a3;
    s += __shfl_xor(s, 1); s += __shfl_xor(s, 2); s += __shfl_xor(s, 4);
    if (t8 == 0) Spart[(size_t)blk * 32u + o] = s;
  }
}

// ---------------- scalar mean of att from block partial sums ----------------
__global__ __launch_bounds__(64) void k_mean(const float* __restrict__ Spart,
                                             const float* __restrict__ bq, const float* __restrict__ bk,
                                             float* __restrict__ meanp) {
  int t = threadIdx.x;        // (b,o): b = t>>4, o = t&15
  int b = t >> 4, o = t & 15;
  float sq = 4096.0f * bq[o], sk = 4096.0f * bk[o];
  for (int blk = 0; blk < 128; ++blk) {
    const float* p = Spart + ((size_t)(b * 128 + blk)) * 32u;
    sq += p[o];
    sk += p[16 + o];
  }
  float pr = sq * sk;
#pragma unroll
  for (int off = 32; off > 0; off >>= 1) pr += __shfl_down(pr, off);
  if (t == 0) *meanp = pr * (1.0f / 67108864.0f);   // / (B*N*N)
}

// ---------------- one-pass MFMA flash: split-bf16 QK^T + masked softmax + PV ----------------
// 256 blocks, XCD-bijective remap: batch = bits1-2 of blockIdx -> each XCD serves ONE batch
// (2 MB V + 256 KB K fit its 4 MB L2). 512 threads = 8 waves (2/SIMD).
__global__ __launch_bounds__(512) void k_flash(const float* __restrict__ qT,
                                               const float* __restrict__ kT,
                                               const u16* __restrict__ vT,
                                               const float* __restrict__ meanp,
                                               float* __restrict__ ods) {
  __shared__ u16 vbuf[2][16384];       // [buf][c row(256) x kv(64)] linear, source-swizzled (64 KB)
  __shared__ u16 kfh[2][4][64][8];     // B-frag [k_hi|k_hi], fragment-linear (8 KB)
  __shared__ u16 kfl[2][4][64][8];     // B-frag [k_lo|k_lo] (8 KB)
  __shared__ u16 pfr[8][2][64][8];     // per-wave P A-frags (16 KB)

  const int orig = blockIdx.x;
  const int b    = (orig >> 1) & 3;                        // bits1-2 -> XCD pair per batch
  const int row0 = (((orig & 1) << 5) | (orig >> 3)) * 64; // bijective q-tile remap
  const int tid  = threadIdx.x;
  const int w    = tid >> 6;
  const int lane = tid & 63;
  const int wq   = w & 3;
  const int wc   = w >> 2;
  const int g    = lane >> 4;          // 0..3
  const int c16  = lane & 15;

  const float mean = *meanp;

  // ---- Q A-frags (split bf16: A1=[q_hi|q_lo], A2=[q_hi|0]) ----
  float qv[16];
  {
    const float* qrow = qT + ((size_t)b*4096 + row0 + 16*wq + c16) * 16;
#pragma unroll
    for (int i = 0; i < 4; ++i) {
      float4 t4 = reinterpret_cast<const float4*>(qrow)[i];
      qv[4*i] = t4.x; qv[4*i+1] = t4.y; qv[4*i+2] = t4.z; qv[4*i+3] = t4.w;
    }
  }
  u16 qhi[16], qlo[16];
#pragma unroll
  for (int i = 0; i < 16; ++i) {
    __hip_bfloat16 h = __float2bfloat16(qv[i]);
    float fh = __bfloat162float(h);
    __hip_bfloat16 lo = __float2bfloat16(qv[i] - fh);
    qhi[i] = __builtin_bit_cast(u16, h);
    qlo[i] = __builtin_bit_cast(u16, lo);
  }
  us8 a1u, a2u;
  {
    const bool koff8  = (g & 1);
    const bool lo_src = (g >= 2);
#pragma unroll
    for (int i = 0; i < 8; ++i) {
      u16 hs = koff8 ? qhi[i+8] : qhi[i];
      u16 ls = koff8 ? qlo[i+8] : qlo[i];
      a1u[i] = lo_src ? ls : hs;
      a2u[i] = lo_src ? (u16)0 : hs;
    }
  }
  const bf16x8 A1 = __builtin_bit_cast(bf16x8, a1u);
  const bf16x8 A2 = __builtin_bit_cast(bf16x8, a2u);

  f32x4 O[8];
#pragma unroll
  for (int i = 0; i < 8; ++i) O[i] = (f32x4){0.f, 0.f, 0.f, 0.f};
  float Lr[4] = {0.f, 0.f, 0.f, 0.f};
  float M = 0.0f;

  // K staging params (threads 0..255 only)
  const int kv_s = tid >> 2, t4v = tid & 3;
  const int ks = kv_s >> 4, kld0 = (kv_s & 15) + 16*(t4v >> 1), ki0 = 4*(t4v & 1);

  // ---- prologue: stage tile 0 ----
  {
    const u16* vsrc = vT + (size_t)b*256*4096;
#pragma unroll
    for (int i = 0; i < 4; ++i) {
      int u = i*512 + tid;
      int row = u >> 3, slot = u & 7;
      int sb = (slot*16) ^ ((row & 7) << 4);
      gl2lds16((const char*)(vsrc + (size_t)row*4096) + sb, (char*)&vbuf[0][0] + u*16);
    }
    if (tid < 256) {
      float4 kvec = *reinterpret_cast<const float4*>(kT + ((size_t)b*4096 + kv_s)*16 + 4*t4v);
      float kf[4] = {kvec.x, kvec.y, kvec.z, kvec.w};
      us4 h4, l4;
#pragma unroll
      for (int di = 0; di < 4; ++di) {
        __hip_bfloat16 h = __float2bfloat16(kf[di]);
        float fh = __bfloat162float(h);
        __hip_bfloat16 lo = __float2bfloat16(kf[di] - fh);
        h4[di] = __builtin_bit_cast(u16, h);
        l4[di] = __builtin_bit_cast(u16, lo);
      }
      *reinterpret_cast<us4*>(&kfh[0][ks][kld0][ki0])    = h4;
      *reinterpret_cast<us4*>(&kfh[0][ks][kld0+32][ki0]) = h4;
      *reinterpret_cast<us4*>(&kfl[0][ks][kld0][ki0])    = l4;
      *reinterpret_cast<us4*>(&kfl[0][ks][kld0+32][ki0]) = l4;
    }
  }
  __syncthreads();

  // ---- main loop over 64 KV tiles of 64 ----
  for (int t = 0; t < 64; ++t) {
    const int cur = t & 1, nxt = cur ^ 1;
    const int kv0n = ((t + 1) & 63) * 64;

    // [D] issue next-tile staging (K -> regs, V -> LDS via DMA)
    float4 kvec;
    if (tid < 256)
      kvec = *reinterpret_cast<const float4*>(kT + ((size_t)b*4096 + kv0n + kv_s)*16 + 4*t4v);
    {
      const u16* vsrc = vT + (size_t)b*256*4096 + kv0n;
#pragma unroll
      for (int i = 0; i < 4; ++i) {
        int u = i*512 + tid;
        int row = u >> 3, slot = u & 7;
        int sb = (slot*16) ^ ((row & 7) << 4);
        gl2lds16((const char*)(vsrc + (size_t)row*4096) + sb, (char*)&vbuf[nxt][0] + u*16);
      }
    }

    // [A] scores: 4 kv-subtiles x 2 MFMA (split-bf16)
    f32x4 S[4];
#pragma unroll
    for (int s = 0; s < 4; ++s) {
      bf16x8 bh = __builtin_bit_cast(bf16x8, *reinterpret_cast<const us8*>(&kfh[cur][s][lane][0]));
      bf16x8 bl = __builtin_bit_cast(bf16x8, *reinterpret_cast<const us8*>(&kfl[cur][s][lane][0]));
      f32x4 acc = (f32x4){0.f, 0.f, 0.f, 0.f};
      acc = __builtin_amdgcn_mfma_f32_16x16x32_bf16(A1, bh, acc, 0, 0, 0);
      acc = __builtin_amdgcn_mfma_f32_16x16x32_bf16(A2, bl, acc, 0, 0, 0);
      S[s] = acc;
    }

    // [B] mask + deferred-max online softmax (wave-wide M, THR=8)
    float pmax = -1e30f;
#pragma unroll
    for (int s = 0; s < 4; ++s)
#pragma unroll
      for (int r = 0; r < 4; ++r) {
        float v = S[s][r];
        v = (v < mean) ? 0.f : v;
        S[s][r] = v;
        pmax = fmaxf(pmax, v);
      }
    if (!__all(pmax <= M + 8.0f)) {
      float mw = pmax;
#pragma unroll
      for (int off = 1; off < 64; off <<= 1) mw = fmaxf(mw, __shfl_xor(mw, off));
      float Mn = fmaxf(M, mw);
      float sc = __expf(M - Mn);
#pragma unroll
      for (int i = 0; i < 8; ++i) {
        O[i][0] *= sc; O[i][1] *= sc; O[i][2] *= sc; O[i][3] *= sc;
      }
#pragma unroll
      for (int r = 0; r < 4; ++r) Lr[r] *= sc;
      M = Mn;
    }
    u16 pb[4][4];
#pragma unroll
    for (int s = 0; s < 4; ++s)
#pragma unroll
      for (int r = 0; r < 4; ++r) {
        float p = __expf(S[s][r] - M);
        Lr[r] += p;
        pb[s][r] = __builtin_bit_cast(u16, __float2bfloat16(p));
      }

    // [C] write P into per-wave A-frag copy
    {
      const int ib = lane & 7;
      const int t1 = (lane >> 3) & 1;
#pragma unroll
      for (int s = 0; s < 4; ++s) {
        const int c2 = s >> 1;
        const int ldb = 16 * ((2*s + t1) & 3) + 4*g;
#pragma unroll
        for (int r = 0; r < 4; ++r) pfr[w][c2][ldb + r][ib] = pb[s][r];
      }
    }
    asm volatile("s_waitcnt lgkmcnt(0)" ::: "memory");
    __builtin_amdgcn_sched_barrier(0);

    // [G] PV: 2 k-chunks x 8 c-subtiles (this wave's c-half)
#pragma unroll
    for (int c2 = 0; c2 < 2; ++c2) {
      bf16x8 pa = __builtin_bit_cast(bf16x8, *reinterpret_cast<const us8*>(&pfr[w][c2][lane][0]));
#pragma unroll
      for (int ct = 0; ct < 8; ++ct) {
        int row = (wc*8 + ct)*16 + c16;
        int off = (c2*64 + g*16) ^ ((lane & 7) << 4);
        bf16x8 vb = __builtin_bit_cast(bf16x8,
            *reinterpret_cast<const us8*>((const char*)&vbuf[cur][0] + row*128 + off));
        O[ct] = __builtin_amdgcn_mfma_f32_16x16x32_bf16(pa, vb, O[ct], 0, 0, 0);
      }
    }

    // [H] convert + write K frags for next tile
    if (tid < 256) {
      float kf[4] = {kvec.x, kvec.y, kvec.z, kvec.w};
      us4 h4, l4;
#pragma unroll
      for (int di = 0; di < 4; ++di) {
        __hip_bfloat16 h = __float2bfloat16(kf[di]);
        float fh = __bfloat162float(h);
        __hip_bfloat16 lo = __float2bfloat16(kf[di] - fh);
        h4[di] = __builtin_bit_cast(u16, h);
        l4[di] = __builtin_bit_cast(u16, lo);
      }
      *reinterpret_cast<us4*>(&kfh[nxt][ks][kld0][ki0])    = h4;
      *reinterpret_cast<us4*>(&kfh[nxt][ks][kld0+32][ki0]) = h4;
      *reinterpret_cast<us4*>(&kfl[nxt][ks][kld0][ki0])    = l4;
      *reinterpret_cast<us4*>(&kfl[nxt][ks][kld0+32][ki0]) = l4;
    }

    __syncthreads();
  }

  // ---- epilogue: reduce L across the 16 kv-lanes, write O/L to ods [b][c][n] ----
#pragma unroll
  for (int r = 0; r < 4; ++r) {
    float v = Lr[r];
#pragma unroll
    for (int off = 1; off < 16; off <<= 1) v += __shfl_xor(v, off);
    Lr[r] = v;
  }
  float inv[4];
#pragma unroll
  for (int r = 0; r < 4; ++r) inv[r] = 1.0f / Lr[r];
#pragma unroll
  for (int ct = 0; ct < 8; ++ct) {
    int c = (wc*8 + ct)*16 + c16;
    float* dst = ods + ((size_t)b*256 + c) * 4096u + row0 + 16*wq + 4*g;
    float4 o4 = make_float4(O[ct][0]*inv[0], O[ct][1]*inv[1], O[ct][2]*inv[2], O[ct][3]*inv[3]);
    *reinterpret_cast<float4*>(dst) = o4;
  }
}

// ---------------- bilinear 4x upsample + residual, 4 px/thread ----------------
__global__ __launch_bounds__(256) void k_up(const float* __restrict__ ods, const float* __restrict__ x,
                                            float* __restrict__ out) {
  unsigned idx4 = blockIdx.x * 256u + threadIdx.x;   // < 16777216
  int a  = (int)(idx4 & 63u);          // horizontal cell = output j strip [4a,4a+4)
  int i  = (int)((idx4 >> 6) & 255u);  // output row
  size_t bc = idx4 >> 14;              // b*256 + c

  float py = (i + 0.5f) * 0.25f - 0.5f;
  float y0f = floorf(py);
  float wy = py - y0f;
  int y0 = (int)y0f, y1 = y0 + 1;
  y0 = max(y0, 0); y1 = min(y1, 63);

  int xm1 = max(a - 1, 0), xp1 = min(a + 1, 63);

  const float* r0 = ods + bc * 4096u + y0 * 64;
  const float* r1 = ods + bc * 4096u + y1 * 64;
  float wy1 = 1.f - wy;
  float vm1 = wy1 * r0[xm1] + wy * r1[xm1];
  float v0  = wy1 * r0[a]   + wy * r1[a];
  float vp1 = wy1 * r0[xp1] + wy * r1[xp1];

  float4 xv = *reinterpret_cast<const float4*>(x + (size_t)idx4 * 4u);
  float4 o4;
  o4.x = fmaf(0.375f, vm1, 0.625f * v0) + xv.x;
  o4.y = fmaf(0.125f, vm1, 0.875f * v0) + xv.y;
  o4.z = fmaf(0.875f, v0, 0.125f * vp1) + xv.z;
  o4.w = fmaf(0.625f, v0, 0.375f * vp1) + xv.w;
  *reinterpret_cast<float4*>(out + (size_t)idx4 * 4u) = o4;
}

extern "C" void kernel_launch(void* const* d_in, const int* in_sizes, int n_in,
                              void* d_out, int out_size, void* d_ws, size_t ws_size,
                              hipStream_t stream) {
  const float* x  = (const float*)d_in[0];
  const float* Wq = (const float*)d_in[1];
  const float* bq = (const float*)d_in[2];
  const float* Wk = (const float*)d_in[3];
  const float* bk = (const float*)d_in[4];
  const float* Wv = (const float*)d_in[5];
  const float* bv = (const float*)d_in[6];
  float* out = (float*)d_out;

  char* ws = (char*)d_ws;
  float* ods   = (float*)(ws + OFF_ODS);
  float* qT    = (float*)(ws + OFF_QT);
  float* kT    = (float*)(ws + OFF_KT);
  u16*   vT    = (u16*)(ws + OFF_VT);
  float* Spart = (float*)(ws + OFF_SPART);
  float* mnp   = (float*)(ws + OFF_MEAN);
  float* WvT   = (float*)(ws + OFF_WVT);

  k_prep<<<dim3(16), dim3(256), 0, stream>>>(Wv, WvT);
  k_front<<<dim3(512), dim3(256), 0, stream>>>(x, WvT, bv, Wq, bq, Wk, bk, qT, kT, vT, Spart);
  k_mean<<<dim3(1), dim3(64), 0, stream>>>(Spart, bq, bk, mnp);
  k_flash<<<dim3(256), dim3(512), 0, stream>>>(qT, kT, vT, mnp, ods);
  k_up<<<dim3(65536), dim3(256), 0, stream>>>(ods, x, out);
}

// Round 13
// 286.586 us; speedup vs baseline: 1.2171x; 1.1179x over previous
//
#include <hip/hip_runtime.h>
#include <hip/hip_bf16.h>
#include <cmath>
#include <cstdint>
#include <cstddef>

// Problem constants: B=4, C=256, H=W=256, DS=4 -> h=w=64, N=4096, Cq=16
typedef unsigned short u16;
typedef __attribute__((ext_vector_type(8))) __bf16 bf16x8;
typedef __attribute__((ext_vector_type(4))) float f32x4;
typedef __attribute__((ext_vector_type(8))) unsigned short us8;
typedef __attribute__((ext_vector_type(4))) unsigned short us4;

// Workspace layout (bytes) — max 27.43 MB (within proven envelope)
static const size_t OFF_XD32  = 0;            // [B][C][4096] fp32 xd; aliased by ods (flash out)
static const size_t OFF_QT    = 16777216;     // [B][4096][16] fp32, 1 MB
static const size_t OFF_KT    = 17825792;     // [B][4096][16] fp32, 1 MB
static const size_t OFF_VT    = 18874368;     // [B][256][4096] bf16 (V transposed), 8 MB
static const size_t OFF_WF    = 27262976;     // Wv A-frags [16 rt][8 ks][64 lane][8 j] bf16, 128 KB
static const size_t OFF_SPART = 27394048;     // [256 blocks][32] fp32 partial col-sums, 32 KB
static const size_t OFF_MEAN  = 27426816;     // 1 float

__device__ __forceinline__ void gl2lds16(const void* gsrc, void* ldst) {
  __builtin_amdgcn_global_load_lds(
      (const __attribute__((address_space(1))) unsigned int*)gsrc,
      (__attribute__((address_space(3))) unsigned int*)ldst, 16, 0, 0);
}

__device__ __forceinline__ float hmax4(float4 v) {
  return fmaxf(fmaxf(v.x, v.y), fmaxf(v.z, v.w));
}

// ---------------- Wv -> MFMA A-fragments (bf16) ----------------
// A-frag convention: lane holds A[row=lane&15][k=(lane>>4)*8+j].
// Wf[rt][ks][lane][j] = Wv[rt*16 + (lane&15)][ks*32 + (lane>>4)*8 + j]
__global__ __launch_bounds__(256) void k_prepw(const float* __restrict__ Wv,
                                               u16* __restrict__ Wf) {
  const int rt = blockIdx.x;           // 0..15
  const int tid = threadIdx.x;
#pragma unroll
  for (int i = 0; i < 2; ++i) {
    int s = tid + i * 256;             // 0..511 = ks*64 + lane
    int ks = s >> 6, lane = s & 63;
    const float* src = Wv + (size_t)(rt * 16 + (lane & 15)) * 256u + ks * 32 + (lane >> 4) * 8;
    float4 a = *reinterpret_cast<const float4*>(src);
    float4 b = *reinterpret_cast<const float4*>(src + 4);
    us8 o;
    o[0] = __builtin_bit_cast(u16, __float2bfloat16(a.x));
    o[1] = __builtin_bit_cast(u16, __float2bfloat16(a.y));
    o[2] = __builtin_bit_cast(u16, __float2bfloat16(a.z));
    o[3] = __builtin_bit_cast(u16, __float2bfloat16(a.w));
    o[4] = __builtin_bit_cast(u16, __float2bfloat16(b.x));
    o[5] = __builtin_bit_cast(u16, __float2bfloat16(b.y));
    o[6] = __builtin_bit_cast(u16, __float2bfloat16(b.z));
    o[7] = __builtin_bit_cast(u16, __float2bfloat16(b.w));
    *reinterpret_cast<us8*>(Wf + ((size_t)((rt * 8 + ks) * 64 + lane)) * 8u) = o;
  }
}

// ---------------- maxpool 4x4 (streaming, 16384 blocks) ----------------
__global__ __launch_bounds__(256) void k_pool(const float* __restrict__ x,
                                              float* __restrict__ xd32) {
  unsigned idx = blockIdx.x * 256u + threadIdx.x;      // < 4*256*64*64
  unsigned xo = idx & 63u;
  unsigned yo = (idx >> 6) & 63u;
  unsigned bc = idx >> 12;                             // b*256 + c
  const float* base = x + (size_t)bc * 65536u + yo * 1024u + xo * 4u;
  float m = -1e30f;
#pragma unroll
  for (int dy = 0; dy < 4; ++dy) {
    float4 v = *reinterpret_cast<const float4*>(base + dy * 256);
    m = fmaxf(m, hmax4(v));
  }
  xd32[(size_t)bc * 4096u + yo * 64u + xo] = m;
}

// ---------------- q/k 1x1 convs (fp32 exact) + col sums ----------------
// 256 blocks (b x 64 strips of 64 tokens) x 512 threads; LDS 64 KB.
__global__ __launch_bounds__(512) void k_qk(const float* __restrict__ xd32,
                                            const float* __restrict__ Wq, const float* __restrict__ bq,
                                            const float* __restrict__ Wk, const float* __restrict__ bk,
                                            float* __restrict__ qT, float* __restrict__ kT,
                                            float* __restrict__ Spart) {
  __shared__ float xs[256][64];
  const int blk = blockIdx.x;
  const int b = blk >> 6, n0 = (blk & 63) * 64;
  const int tid = threadIdx.x;
  {
    const float* src = xd32 + (size_t)b * 1048576u + n0;
#pragma unroll
    for (int i = 0; i < 8; ++i) {
      int slot = tid + i * 512;        // 0..4095 float4 slots
      int c = slot >> 4, q4 = slot & 15;
      *reinterpret_cast<float4*>(&xs[c][q4 * 4]) =
          *reinterpret_cast<const float4*>(src + (size_t)c * 4096u + q4 * 4);
    }
  }
  __syncthreads();
  const int o = tid >> 4, t4 = tid & 15;   // o 0..31; tokens t4*4..+4
  const float* wrow = (o < 16) ? (Wq + (size_t)o * 256u) : (Wk + (size_t)(o - 16) * 256u);
  float a0 = 0.f, a1 = 0.f, a2 = 0.f, a3 = 0.f;
  for (int c = 0; c < 256; ++c) {
    float w = wrow[c];
    float4 xv = *reinterpret_cast<const float4*>(&xs[c][t4 * 4]);
    a0 = fmaf(w, xv.x, a0);
    a1 = fmaf(w, xv.y, a1);
    a2 = fmaf(w, xv.z, a2);
    a3 = fmaf(w, xv.w, a3);
  }
  float* dst = (o < 16) ? qT : kT;
  int oo = (o < 16) ? o : (o - 16);
  float bb = (o < 16) ? bq[oo] : bk[oo];
  size_t base = ((size_t)b * 4096u + n0 + t4 * 4) * 16u + oo;
  dst[base]      = a0 + bb;
  dst[base + 16] = a1 + bb;
  dst[base + 32] = a2 + bb;
  dst[base + 48] = a3 + bb;
  // col sums over the strip (bias added in k_mean)
  float s = a0 + a1 + a2 + a3;
  s += __shfl_xor(s, 1); s += __shfl_xor(s, 2);
  s += __shfl_xor(s, 4); s += __shfl_xor(s, 8);
  if (t4 == 0) Spart[(size_t)blk * 32u + o] = s;
}

// ---------------- V = Wv * xd via MFMA (bf16 in, fp32 accum) ----------------
// 256 blocks (b x 64 n-tiles of 64 tokens) x 256 threads (4 waves).
// B-frags staged from fp32 xd with on-the-fly bf16 convert (FULL k coverage, 16 iters).
__global__ __launch_bounds__(256) void k_vgemm(const float* __restrict__ xd32,
                                               const u16* __restrict__ Wf,
                                               const float* __restrict__ bv,
                                               u16* __restrict__ vT) {
  __shared__ u16 Bf[4][8][64][8];      // B-frags: 32 KB
  const int blk = blockIdx.x;
  const int b = blk >> 6, n0 = (blk & 63) * 64;
  const int tid = threadIdx.x;
  const int w = tid >> 6, lane = tid & 63;

  // ---- stage B-frags: Bf[ct][ks][lane][j] = bf16(xd[k=ks*32+(lane>>4)*8+j][n0+ct*16+(lane&15)]) ----
#pragma unroll
  for (int p = 0; p < 16; ++p) {
    int idx = p * 256 + tid;           // 0..4095 float4 slots (k x 16 n-chunks)
    int k = idx >> 4, q4 = idx & 15;
    float4 v = *reinterpret_cast<const float4*>(
        xd32 + ((size_t)b * 256 + k) * 4096u + n0 + q4 * 4);
    int ks = k >> 5, kl = (k >> 3) & 3, j = k & 7;
    int ct = q4 >> 2, nb = (q4 & 3) * 4;
    Bf[ct][ks][kl * 16 + nb + 0][j] = __builtin_bit_cast(u16, __float2bfloat16(v.x));
    Bf[ct][ks][kl * 16 + nb + 1][j] = __builtin_bit_cast(u16, __float2bfloat16(v.y));
    Bf[ct][ks][kl * 16 + nb + 2][j] = __builtin_bit_cast(u16, __float2bfloat16(v.z));
    Bf[ct][ks][kl * 16 + nb + 3][j] = __builtin_bit_cast(u16, __float2bfloat16(v.w));
  }
  __syncthreads();

  // ---- MFMA: 4 rt x 4 ct x 8 ks ----
  f32x4 acc[4][4];
#pragma unroll
  for (int r = 0; r < 4; ++r)
#pragma unroll
    for (int ct = 0; ct < 4; ++ct) acc[r][ct] = (f32x4){0.f, 0.f, 0.f, 0.f};
  for (int ks = 0; ks < 8; ++ks) {
    bf16x8 Bv[4];
#pragma unroll
    for (int ct = 0; ct < 4; ++ct)
      Bv[ct] = __builtin_bit_cast(bf16x8, *reinterpret_cast<const us8*>(&Bf[ct][ks][lane][0]));
#pragma unroll
    for (int r = 0; r < 4; ++r) {
      int rt = w * 4 + r;
      bf16x8 Av = __builtin_bit_cast(bf16x8,
          *reinterpret_cast<const us8*>(Wf + ((size_t)((rt * 8 + ks) * 64 + lane)) * 8u));
#pragma unroll
      for (int ct = 0; ct < 4; ++ct)
        acc[r][ct] = __builtin_amdgcn_mfma_f32_16x16x32_bf16(Av, Bv[ct], acc[r][ct], 0, 0, 0);
    }
  }

  // ---- epilogue: D row=(lane>>4)*4+rr, col=lane&15 ----
#pragma unroll
  for (int r = 0; r < 4; ++r) {
    int row0 = (w * 4 + r) * 16 + (lane >> 4) * 4;
#pragma unroll
    for (int rr = 0; rr < 4; ++rr) {
      int c = row0 + rr;
      float bb = bv[c];
      u16* dst = vT + ((size_t)b * 256 + c) * 4096u + n0 + (lane & 15);
#pragma unroll
      for (int ct = 0; ct < 4; ++ct)
        dst[ct * 16] = __builtin_bit_cast(u16, __float2bfloat16(acc[r][ct][rr] + bb));
    }
  }
}

// ---------------- scalar mean of att from block partial sums ----------------
__global__ __launch_bounds__(64) void k_mean(const float* __restrict__ Spart,
                                             const float* __restrict__ bq, const float* __restrict__ bk,
                                             float* __restrict__ meanp) {
  int t = threadIdx.x;        // (b,o): b = t>>4, o = t&15
  int b = t >> 4, o = t & 15;
  float sq = 4096.0f * bq[o], sk = 4096.0f * bk[o];
  for (int blk = 0; blk < 64; ++blk) {
    const float* p = Spart + ((size_t)(b * 64 + blk)) * 32u;
    sq += p[o];
    sk += p[16 + o];
  }
  float pr = sq * sk;
#pragma unroll
  for (int off = 32; off > 0; off >>= 1) pr += __shfl_down(pr, off);
  if (t == 0) *meanp = pr * (1.0f / 67108864.0f);   // / (B*N*N)
}

// ---------------- one-pass MFMA flash: split-bf16 QK^T + masked softmax + PV ----------------
// 256 blocks, XCD-bijective remap: batch = bits1-2 of blockIdx -> each XCD serves ONE batch.
// 512 threads = 8 waves (2/SIMD).
__global__ __launch_bounds__(512) void k_flash(const float* __restrict__ qT,
                                               const float* __restrict__ kT,
                                               const u16* __restrict__ vT,
                                               const float* __restrict__ meanp,
                                               float* __restrict__ ods) {
  __shared__ u16 vbuf[2][16384];       // [buf][c row(256) x kv(64)] linear, source-swizzled (64 KB)
  __shared__ u16 kfh[2][4][64][8];     // B-frag [k_hi|k_hi], fragment-linear (8 KB)
  __shared__ u16 kfl[2][4][64][8];     // B-frag [k_lo|k_lo] (8 KB)
  __shared__ u16 pfr[8][2][64][8];     // per-wave P A-frags (16 KB)

  const int orig = blockIdx.x;
  const int b    = (orig >> 1) & 3;                        // bits1-2 -> XCD pair per batch
  const int row0 = (((orig & 1) << 5) | (orig >> 3)) * 64; // bijective q-tile remap
  const int tid  = threadIdx.x;
  const int w    = tid >> 6;
  const int lane = tid & 63;
  const int wq   = w & 3;
  const int wc   = w >> 2;
  const int g    = lane >> 4;          // 0..3
  const int c16  = lane & 15;

  const float mean = *meanp;

  // ---- Q A-frags (split bf16: A1=[q_hi|q_lo], A2=[q_hi|0]) ----
  float qv[16];
  {
    const float* qrow = qT + ((size_t)b*4096 + row0 + 16*wq + c16) * 16;
#pragma unroll
    for (int i = 0; i < 4; ++i) {
      float4 t4 = reinterpret_cast<const float4*>(qrow)[i];
      qv[4*i] = t4.x; qv[4*i+1] = t4.y; qv[4*i+2] = t4.z; qv[4*i+3] = t4.w;
    }
  }
  u16 qhi[16], qlo[16];
#pragma unroll
  for (int i = 0; i < 16; ++i) {
    __hip_bfloat16 h = __float2bfloat16(qv[i]);
    float fh = __bfloat162float(h);
    __hip_bfloat16 lo = __float2bfloat16(qv[i] - fh);
    qhi[i] = __builtin_bit_cast(u16, h);
    qlo[i] = __builtin_bit_cast(u16, lo);
  }
  us8 a1u, a2u;
  {
    const bool koff8  = (g & 1);
    const bool lo_src = (g >= 2);
#pragma unroll
    for (int i = 0; i < 8; ++i) {
      u16 hs = koff8 ? qhi[i+8] : qhi[i];
      u16 ls = koff8 ? qlo[i+8] : qlo[i];
      a1u[i] = lo_src ? ls : hs;
      a2u[i] = lo_src ? (u16)0 : hs;
    }
  }
  const bf16x8 A1 = __builtin_bit_cast(bf16x8, a1u);
  const bf16x8 A2 = __builtin_bit_cast(bf16x8, a2u);

  f32x4 O[8];
#pragma unroll
  for (int i = 0; i < 8; ++i) O[i] = (f32x4){0.f, 0.f, 0.f, 0.f};
  float Lr[4] = {0.f, 0.f, 0.f, 0.f};
  float M = 0.0f;

  // K staging params (threads 0..255 only)
  const int kv_s = tid >> 2, t4v = tid & 3;
  const int ks = kv_s >> 4, kld0 = (kv_s & 15) + 16*(t4v >> 1), ki0 = 4*(t4v & 1);

  // ---- prologue: stage tile 0 ----
  {
    const u16* vsrc = vT + (size_t)b*256*4096;
#pragma unroll
    for (int i = 0; i < 4; ++i) {
      int u = i*512 + tid;
      int row = u >> 3, slot = u & 7;
      int sb = (slot*16) ^ ((row & 7) << 4);
      gl2lds16((const char*)(vsrc + (size_t)row*4096) + sb, (char*)&vbuf[0][0] + u*16);
    }
    if (tid < 256) {
      float4 kvec = *reinterpret_cast<const float4*>(kT + ((size_t)b*4096 + kv_s)*16 + 4*t4v);
      float kf[4] = {kvec.x, kvec.y, kvec.z, kvec.w};
      us4 h4, l4;
#pragma unroll
      for (int di = 0; di < 4; ++di) {
        __hip_bfloat16 h = __float2bfloat16(kf[di]);
        float fh = __bfloat162float(h);
        __hip_bfloat16 lo = __float2bfloat16(kf[di] - fh);
        h4[di] = __builtin_bit_cast(u16, h);
        l4[di] = __builtin_bit_cast(u16, lo);
      }
      *reinterpret_cast<us4*>(&kfh[0][ks][kld0][ki0])    = h4;
      *reinterpret_cast<us4*>(&kfh[0][ks][kld0+32][ki0]) = h4;
      *reinterpret_cast<us4*>(&kfl[0][ks][kld0][ki0])    = l4;
      *reinterpret_cast<us4*>(&kfl[0][ks][kld0+32][ki0]) = l4;
    }
  }
  __syncthreads();

  // ---- main loop over 64 KV tiles of 64 ----
  for (int t = 0; t < 64; ++t) {
    const int cur = t & 1, nxt = cur ^ 1;
    const int kv0n = ((t + 1) & 63) * 64;

    // [D] issue next-tile staging (K -> regs, V -> LDS via DMA)
    float4 kvec;
    if (tid < 256)
      kvec = *reinterpret_cast<const float4*>(kT + ((size_t)b*4096 + kv0n + kv_s)*16 + 4*t4v);
    {
      const u16* vsrc = vT + (size_t)b*256*4096 + kv0n;
#pragma unroll
      for (int i = 0; i < 4; ++i) {
        int u = i*512 + tid;
        int row = u >> 3, slot = u & 7;
        int sb = (slot*16) ^ ((row & 7) << 4);
        gl2lds16((const char*)(vsrc + (size_t)row*4096) + sb, (char*)&vbuf[nxt][0] + u*16);
      }
    }

    // [A] scores: 4 kv-subtiles x 2 MFMA (split-bf16)
    f32x4 S[4];
#pragma unroll
    for (int s = 0; s < 4; ++s) {
      bf16x8 bh = __builtin_bit_cast(bf16x8, *reinterpret_cast<const us8*>(&kfh[cur][s][lane][0]));
      bf16x8 bl = __builtin_bit_cast(bf16x8, *reinterpret_cast<const us8*>(&kfl[cur][s][lane][0]));
      f32x4 acc = (f32x4){0.f, 0.f, 0.f, 0.f};
      acc = __builtin_amdgcn_mfma_f32_16x16x32_bf16(A1, bh, acc, 0, 0, 0);
      acc = __builtin_amdgcn_mfma_f32_16x16x32_bf16(A2, bl, acc, 0, 0, 0);
      S[s] = acc;
    }

    // [B] mask + deferred-max online softmax (wave-wide M, THR=8)
    float pmax = -1e30f;
#pragma unroll
    for (int s = 0; s < 4; ++s)
#pragma unroll
      for (int r = 0; r < 4; ++r) {
        float v = S[s][r];
        v = (v < mean) ? 0.f : v;
        S[s][r] = v;
        pmax = fmaxf(pmax, v);
      }
    if (!__all(pmax <= M + 8.0f)) {
      float mw = pmax;
#pragma unroll
      for (int off = 1; off < 64; off <<= 1) mw = fmaxf(mw, __shfl_xor(mw, off));
      float Mn = fmaxf(M, mw);
      float sc = __expf(M - Mn);
#pragma unroll
      for (int i = 0; i < 8; ++i) {
        O[i][0] *= sc; O[i][1] *= sc; O[i][2] *= sc; O[i][3] *= sc;
      }
#pragma unroll
      for (int r = 0; r < 4; ++r) Lr[r] *= sc;
      M = Mn;
    }
    u16 pb[4][4];
#pragma unroll
    for (int s = 0; s < 4; ++s)
#pragma unroll
      for (int r = 0; r < 4; ++r) {
        float p = __expf(S[s][r] - M);
        Lr[r] += p;
        pb[s][r] = __builtin_bit_cast(u16, __float2bfloat16(p));
      }

    // [C] write P into per-wave A-frag copy
    {
      const int ib = lane & 7;
      const int t1 = (lane >> 3) & 1;
#pragma unroll
      for (int s = 0; s < 4; ++s) {
        const int c2 = s >> 1;
        const int ldb = 16 * ((2*s + t1) & 3) + 4*g;
#pragma unroll
        for (int r = 0; r < 4; ++r) pfr[w][c2][ldb + r][ib] = pb[s][r];
      }
    }
    asm volatile("s_waitcnt lgkmcnt(0)" ::: "memory");
    __builtin_amdgcn_sched_barrier(0);

    // [G] PV: 2 k-chunks x 8 c-subtiles (this wave's c-half)
#pragma unroll
    for (int c2 = 0; c2 < 2; ++c2) {
      bf16x8 pa = __builtin_bit_cast(bf16x8, *reinterpret_cast<const us8*>(&pfr[w][c2][lane][0]));
#pragma unroll
      for (int ct = 0; ct < 8; ++ct) {
        int row = (wc*8 + ct)*16 + c16;
        int off = (c2*64 + g*16) ^ ((lane & 7) << 4);
        bf16x8 vb = __builtin_bit_cast(bf16x8,
            *reinterpret_cast<const us8*>((const char*)&vbuf[cur][0] + row*128 + off));
        O[ct] = __builtin_amdgcn_mfma_f32_16x16x32_bf16(pa, vb, O[ct], 0, 0, 0);
      }
    }

    // [H] convert + write K frags for next tile
    if (tid < 256) {
      float kf[4] = {kvec.x, kvec.y, kvec.z, kvec.w};
      us4 h4, l4;
#pragma unroll
      for (int di = 0; di < 4; ++di) {
        __hip_bfloat16 h = __float2bfloat16(kf[di]);
        float fh = __bfloat162float(h);
        __hip_bfloat16 lo = __float2bfloat16(kf[di] - fh);
        h4[di] = __builtin_bit_cast(u16, h);
        l4[di] = __builtin_bit_cast(u16, lo);
      }
      *reinterpret_cast<us4*>(&kfh[nxt][ks][kld0][ki0])    = h4;
      *reinterpret_cast<us4*>(&kfh[nxt][ks][kld0+32][ki0]) = h4;
      *reinterpret_cast<us4*>(&kfl[nxt][ks][kld0][ki0])    = l4;
      *reinterpret_cast<us4*>(&kfl[nxt][ks][kld0+32][ki0]) = l4;
    }

    __syncthreads();
  }

  // ---- epilogue: reduce L across the 16 kv-lanes, write O/L to ods [b][c][n] ----
#pragma unroll
  for (int r = 0; r < 4; ++r) {
    float v = Lr[r];
#pragma unroll
    for (int off = 1; off < 16; off <<= 1) v += __shfl_xor(v, off);
    Lr[r] = v;
  }
  float inv[4];
#pragma unroll
  for (int r = 0; r < 4; ++r) inv[r] = 1.0f / Lr[r];
#pragma unroll
  for (int ct = 0; ct < 8; ++ct) {
    int c = (wc*8 + ct)*16 + c16;
    float* dst = ods + ((size_t)b*256 + c) * 4096u + row0 + 16*wq + 4*g;
    float4 o4 = make_float4(O[ct][0]*inv[0], O[ct][1]*inv[1], O[ct][2]*inv[2], O[ct][3]*inv[3]);
    *reinterpret_cast<float4*>(dst) = o4;
  }
}

// ---------------- bilinear 4x upsample + residual, 4 px/thread ----------------
__global__ __launch_bounds__(256) void k_up(const float* __restrict__ ods, const float* __restrict__ x,
                                            float* __restrict__ out) {
  unsigned idx4 = blockIdx.x * 256u + threadIdx.x;   // < 16777216
  int a  = (int)(idx4 & 63u);          // horizontal cell = output j strip [4a,4a+4)
  int i  = (int)((idx4 >> 6) & 255u);  // output row
  size_t bc = idx4 >> 14;              // b*256 + c

  float py = (i + 0.5f) * 0.25f - 0.5f;
  float y0f = floorf(py);
  float wy = py - y0f;
  int y0 = (int)y0f, y1 = y0 + 1;
  y0 = max(y0, 0); y1 = min(y1, 63);

  int xm1 = max(a - 1, 0), xp1 = min(a + 1, 63);

  const float* r0 = ods + bc * 4096u + y0 * 64;
  const float* r1 = ods + bc * 4096u + y1 * 64;
  float wy1 = 1.f - wy;
  float vm1 = wy1 * r0[xm1] + wy * r1[xm1];
  float v0  = wy1 * r0[a]   + wy * r1[a];
  float vp1 = wy1 * r0[xp1] + wy * r1[xp1];

  float4 xv = *reinterpret_cast<const float4*>(x + (size_t)idx4 * 4u);
  float4 o4;
  o4.x = fmaf(0.375f, vm1, 0.625f * v0) + xv.x;
  o4.y = fmaf(0.125f, vm1, 0.875f * v0) + xv.y;
  o4.z = fmaf(0.875f, v0, 0.125f * vp1) + xv.z;
  o4.w = fmaf(0.625f, v0, 0.375f * vp1) + xv.w;
  *reinterpret_cast<float4*>(out + (size_t)idx4 * 4u) = o4;
}

extern "C" void kernel_launch(void* const* d_in, const int* in_sizes, int n_in,
                              void* d_out, int out_size, void* d_ws, size_t ws_size,
                              hipStream_t stream) {
  const float* x  = (const float*)d_in[0];
  const float* Wq = (const float*)d_in[1];
  const float* bq = (const float*)d_in[2];
  const float* Wk = (const float*)d_in[3];
  const float* bk = (const float*)d_in[4];
  const float* Wv = (const float*)d_in[5];
  const float* bv = (const float*)d_in[6];
  float* out = (float*)d_out;

  char* ws = (char*)d_ws;
  float* xd32  = (float*)(ws + OFF_XD32);   // aliased by ods after k_vgemm
  float* qT    = (float*)(ws + OFF_QT);
  float* kT    = (float*)(ws + OFF_KT);
  u16*   vT    = (u16*)(ws + OFF_VT);
  u16*   Wf    = (u16*)(ws + OFF_WF);
  float* Spart = (float*)(ws + OFF_SPART);
  float* mnp   = (float*)(ws + OFF_MEAN);
  float* ods   = xd32;

  k_prepw<<<dim3(16), dim3(256), 0, stream>>>(Wv, Wf);
  k_pool<<<dim3(16384), dim3(256), 0, stream>>>(x, xd32);
  k_qk<<<dim3(256), dim3(512), 0, stream>>>(xd32, Wq, bq, Wk, bk, qT, kT, Spart);
  k_vgemm<<<dim3(256), dim3(256), 0, stream>>>(xd32, Wf, bv, vT);
  k_mean<<<dim3(1), dim3(64), 0, stream>>>(Spart, bq, bk, mnp);
  k_flash<<<dim3(256), dim3(512), 0, stream>>>(qT, kT, vT, mnp, ods);
  k_up<<<dim3(65536), dim3(256), 0, stream>>>(ods, x, out);
}

// Round 14
// 280.805 us; speedup vs baseline: 1.2422x; 1.0206x over previous
//
#include <hip/hip_runtime.h>
#include <hip/hip_bf16.h>
#include <cmath>
#include <cstdint>
#include <cstddef>

// Problem constants: B=4, C=256, H=W=256, DS=4 -> h=w=64, N=4096, Cq=16
typedef unsigned short u16;
typedef __attribute__((ext_vector_type(8))) __bf16 bf16x8;
typedef __attribute__((ext_vector_type(4))) float f32x4;
typedef __attribute__((ext_vector_type(8))) unsigned short us8;
typedef __attribute__((ext_vector_type(4))) unsigned short us4;

// Workspace layout (bytes)
static const size_t OFF_XD32  = 0;            // [B][C][4096] fp32 xd; aliased by ods (flash out)
static const size_t OFF_QT    = 16777216;     // [B][4096][16] fp32, 1 MB
static const size_t OFF_KT    = 17825792;     // [B][4096][16] fp32, 1 MB
static const size_t OFF_VT    = 18874368;     // [B][256][4096] bf16 (V transposed), 8 MB
static const size_t OFF_WF    = 27262976;     // Wv A-frags [16 rt][8 ks][64 lane][8 j] bf16, 128 KB
static const size_t OFF_SPART = 27394048;     // [256 qk-blocks][32] fp32 partial col-sums, 32 KB

__device__ __forceinline__ void gl2lds16(const void* gsrc, void* ldst) {
  __builtin_amdgcn_global_load_lds(
      (const __attribute__((address_space(1))) unsigned int*)gsrc,
      (__attribute__((address_space(3))) unsigned int*)ldst, 16, 0, 0);
}

__device__ __forceinline__ float hmax4(float4 v) {
  return fmaxf(fmaxf(v.x, v.y), fmaxf(v.z, v.w));
}

// ---------------- Wv -> MFMA A-fragments (bf16) ----------------
// Wf[rt][ks][lane][j] = Wv[rt*16 + (lane&15)][ks*32 + (lane>>4)*8 + j]
__global__ __launch_bounds__(256) void k_prepw(const float* __restrict__ Wv,
                                               u16* __restrict__ Wf) {
  const int rt = blockIdx.x;           // 0..15
  const int tid = threadIdx.x;
#pragma unroll
  for (int i = 0; i < 2; ++i) {
    int s = tid + i * 256;             // 0..511 = ks*64 + lane
    int ks = s >> 6, lane = s & 63;
    const float* src = Wv + (size_t)(rt * 16 + (lane & 15)) * 256u + ks * 32 + (lane >> 4) * 8;
    float4 a = *reinterpret_cast<const float4*>(src);
    float4 b = *reinterpret_cast<const float4*>(src + 4);
    us8 o;
    o[0] = __builtin_bit_cast(u16, __float2bfloat16(a.x));
    o[1] = __builtin_bit_cast(u16, __float2bfloat16(a.y));
    o[2] = __builtin_bit_cast(u16, __float2bfloat16(a.z));
    o[3] = __builtin_bit_cast(u16, __float2bfloat16(a.w));
    o[4] = __builtin_bit_cast(u16, __float2bfloat16(b.x));
    o[5] = __builtin_bit_cast(u16, __float2bfloat16(b.y));
    o[6] = __builtin_bit_cast(u16, __float2bfloat16(b.z));
    o[7] = __builtin_bit_cast(u16, __float2bfloat16(b.w));
    *reinterpret_cast<us8*>(Wf + ((size_t)((rt * 8 + ks) * 64 + lane)) * 8u) = o;
  }
}

// ---------------- maxpool 4x4 (streaming, 16384 blocks) ----------------
__global__ __launch_bounds__(256) void k_pool(const float* __restrict__ x,
                                              float* __restrict__ xd32) {
  unsigned idx = blockIdx.x * 256u + threadIdx.x;      // < 4*256*64*64
  unsigned xo = idx & 63u;
  unsigned yo = (idx >> 6) & 63u;
  unsigned bc = idx >> 12;                             // b*256 + c
  const float* base = x + (size_t)bc * 65536u + yo * 1024u + xo * 4u;
  float m = -1e30f;
#pragma unroll
  for (int dy = 0; dy < 4; ++dy) {
    float4 v = *reinterpret_cast<const float4*>(base + dy * 256);
    m = fmaxf(m, hmax4(v));
  }
  xd32[(size_t)bc * 4096u + yo * 64u + xo] = m;
}

// ---------------- fused q/k convs + V MFMA gemm (block-role split) ----------------
// 512 blocks x 512 threads. Blocks [0,256): vgemm role. Blocks [256,512): qk role.
// Roles use different pipes (MFMA vs VALU) -> co-scheduled blocks overlap.
__global__ __launch_bounds__(512) void k_qkv(const float* __restrict__ xd32,
                                             const u16* __restrict__ Wf, const float* __restrict__ bv,
                                             const float* __restrict__ Wq, const float* __restrict__ bq,
                                             const float* __restrict__ Wk, const float* __restrict__ bk,
                                             float* __restrict__ qT, float* __restrict__ kT,
                                             u16* __restrict__ vT, float* __restrict__ Spart) {
  __shared__ char smem[65536];
  const int tid = threadIdx.x;

  if (blockIdx.x < 256) {
    // ---------- vgemm role: V = Wv * xd, bf16 MFMA ----------
    u16 (*Bf)[8][64][8] = reinterpret_cast<u16(*)[8][64][8]>(smem);   // [4ct][8ks][64][8] = 32 KB
    const int blk = blockIdx.x;
    const int b = blk >> 6, n0 = (blk & 63) * 64;
    const int w = tid >> 6, lane = tid & 63;

    // stage B-frags: Bf[ct][ks][lane][j] = bf16(xd[k=ks*32+(lane>>4)*8+j][n0+ct*16+(lane&15)])
#pragma unroll
    for (int p = 0; p < 8; ++p) {
      int idx = p * 512 + tid;         // 0..4095 float4 slots
      int k = idx >> 4, q4 = idx & 15;
      float4 v = *reinterpret_cast<const float4*>(
          xd32 + ((size_t)b * 256 + k) * 4096u + n0 + q4 * 4);
      int ks = k >> 5, kl = (k >> 3) & 3, j = k & 7;
      int ct = q4 >> 2, nb = (q4 & 3) * 4;
      Bf[ct][ks][kl * 16 + nb + 0][j] = __builtin_bit_cast(u16, __float2bfloat16(v.x));
      Bf[ct][ks][kl * 16 + nb + 1][j] = __builtin_bit_cast(u16, __float2bfloat16(v.y));
      Bf[ct][ks][kl * 16 + nb + 2][j] = __builtin_bit_cast(u16, __float2bfloat16(v.z));
      Bf[ct][ks][kl * 16 + nb + 3][j] = __builtin_bit_cast(u16, __float2bfloat16(v.w));
    }
    __syncthreads();

    // MFMA: wave w -> rt = 2w, 2w+1; 4 ct; 8 ks
    f32x4 acc[2][4];
#pragma unroll
    for (int r = 0; r < 2; ++r)
#pragma unroll
      for (int ct = 0; ct < 4; ++ct) acc[r][ct] = (f32x4){0.f, 0.f, 0.f, 0.f};
    for (int ks = 0; ks < 8; ++ks) {
      bf16x8 Bv[4];
#pragma unroll
      for (int ct = 0; ct < 4; ++ct)
        Bv[ct] = __builtin_bit_cast(bf16x8, *reinterpret_cast<const us8*>(&Bf[ct][ks][lane][0]));
#pragma unroll
      for (int r = 0; r < 2; ++r) {
        int rt = w * 2 + r;
        bf16x8 Av = __builtin_bit_cast(bf16x8,
            *reinterpret_cast<const us8*>(Wf + ((size_t)((rt * 8 + ks) * 64 + lane)) * 8u));
#pragma unroll
        for (int ct = 0; ct < 4; ++ct)
          acc[r][ct] = __builtin_amdgcn_mfma_f32_16x16x32_bf16(Av, Bv[ct], acc[r][ct], 0, 0, 0);
      }
    }

    // epilogue: D row=(lane>>4)*4+rr, col=lane&15
#pragma unroll
    for (int r = 0; r < 2; ++r) {
      int row0 = (w * 2 + r) * 16 + (lane >> 4) * 4;
#pragma unroll
      for (int rr = 0; rr < 4; ++rr) {
        int c = row0 + rr;
        float bb = bv[c];
        u16* dst = vT + ((size_t)b * 256 + c) * 4096u + n0 + (lane & 15);
#pragma unroll
        for (int ct = 0; ct < 4; ++ct)
          dst[ct * 16] = __builtin_bit_cast(u16, __float2bfloat16(acc[r][ct][rr] + bb));
      }
    }
  } else {
    // ---------- qk role: fp32 exact convs + col sums ----------
    float (*xs)[64] = reinterpret_cast<float(*)[64]>(smem);   // [256][64] = 64 KB
    const int qb = blockIdx.x - 256;
    const int b = qb >> 6, n0 = (qb & 63) * 64;
    {
      const float* src = xd32 + (size_t)b * 1048576u + n0;
#pragma unroll
      for (int i = 0; i < 8; ++i) {
        int slot = tid + i * 512;      // 0..4095 float4 slots
        int c = slot >> 4, q4 = slot & 15;
        *reinterpret_cast<float4*>(&xs[c][q4 * 4]) =
            *reinterpret_cast<const float4*>(src + (size_t)c * 4096u + q4 * 4);
      }
    }
    __syncthreads();
    const int o = tid >> 4, t4 = tid & 15;   // o 0..31; tokens t4*4..+4
    const float* wrow = (o < 16) ? (Wq + (size_t)o * 256u) : (Wk + (size_t)(o - 16) * 256u);
    float a0 = 0.f, a1 = 0.f, a2 = 0.f, a3 = 0.f;
    for (int c = 0; c < 256; ++c) {
      float w = wrow[c];
      float4 xv = *reinterpret_cast<const float4*>(&xs[c][t4 * 4]);
      a0 = fmaf(w, xv.x, a0);
      a1 = fmaf(w, xv.y, a1);
      a2 = fmaf(w, xv.z, a2);
      a3 = fmaf(w, xv.w, a3);
    }
    float* dst = (o < 16) ? qT : kT;
    int oo = (o < 16) ? o : (o - 16);
    float bb = (o < 16) ? bq[oo] : bk[oo];
    size_t base = ((size_t)b * 4096u + n0 + t4 * 4) * 16u + oo;
    dst[base]      = a0 + bb;
    dst[base + 16] = a1 + bb;
    dst[base + 32] = a2 + bb;
    dst[base + 48] = a3 + bb;
    float s = a0 + a1 + a2 + a3;
    s += __shfl_xor(s, 1); s += __shfl_xor(s, 2);
    s += __shfl_xor(s, 4); s += __shfl_xor(s, 8);
    if (t4 == 0) Spart[(size_t)qb * 32u + o] = s;
  }
}

// ---------------- one-pass MFMA flash: split-bf16 QK^T + masked softmax + PV ----------------
// 256 blocks, XCD-bijective remap; 512 threads = 8 waves. Mean computed inline from Spart.
__global__ __launch_bounds__(512) void k_flash(const float* __restrict__ qT,
                                               const float* __restrict__ kT,
                                               const u16* __restrict__ vT,
                                               const float* __restrict__ Spart,
                                               const float* __restrict__ bq,
                                               const float* __restrict__ bk,
                                               float* __restrict__ ods) {
  __shared__ u16 vbuf[2][16384];       // 64 KB
  __shared__ u16 kfh[2][4][64][8];     // 8 KB
  __shared__ u16 kfl[2][4][64][8];     // 8 KB
  __shared__ u16 pfr[8][2][64][8];     // 16 KB
  __shared__ float mean_s;

  const int orig = blockIdx.x;
  const int b    = (orig >> 1) & 3;
  const int row0 = (((orig & 1) << 5) | (orig >> 3)) * 64;
  const int tid  = threadIdx.x;
  const int w    = tid >> 6;
  const int lane = tid & 63;
  const int wq   = w & 3;
  const int wc   = w >> 2;
  const int g    = lane >> 4;
  const int c16  = lane & 15;

  // ---- inline mean of att from Spart (deterministic fixed-order reduce) ----
  if (tid < 64) {
    int bb = tid >> 4, o = tid & 15;
    float sq = 4096.0f * bq[o], sk = 4096.0f * bk[o];
    for (int s = 0; s < 64; ++s) {
      const float* p = Spart + ((size_t)(bb * 64 + s)) * 32u;
      sq += p[o];
      sk += p[16 + o];
    }
    float pr = sq * sk;
#pragma unroll
    for (int off = 32; off > 0; off >>= 1) pr += __shfl_down(pr, off);
    if (tid == 0) mean_s = pr * (1.0f / 67108864.0f);   // / (B*N*N)
  }

  // ---- Q A-frags (split bf16) ----
  float qv[16];
  {
    const float* qrow = qT + ((size_t)b*4096 + row0 + 16*wq + c16) * 16;
#pragma unroll
    for (int i = 0; i < 4; ++i) {
      float4 t4 = reinterpret_cast<const float4*>(qrow)[i];
      qv[4*i] = t4.x; qv[4*i+1] = t4.y; qv[4*i+2] = t4.z; qv[4*i+3] = t4.w;
    }
  }
  u16 qhi[16], qlo[16];
#pragma unroll
  for (int i = 0; i < 16; ++i) {
    __hip_bfloat16 h = __float2bfloat16(qv[i]);
    float fh = __bfloat162float(h);
    __hip_bfloat16 lo = __float2bfloat16(qv[i] - fh);
    qhi[i] = __builtin_bit_cast(u16, h);
    qlo[i] = __builtin_bit_cast(u16, lo);
  }
  us8 a1u, a2u;
  {
    const bool koff8  = (g & 1);
    const bool lo_src = (g >= 2);
#pragma unroll
    for (int i = 0; i < 8; ++i) {
      u16 hs = koff8 ? qhi[i+8] : qhi[i];
      u16 ls = koff8 ? qlo[i+8] : qlo[i];
      a1u[i] = lo_src ? ls : hs;
      a2u[i] = lo_src ? (u16)0 : hs;
    }
  }
  const bf16x8 A1 = __builtin_bit_cast(bf16x8, a1u);
  const bf16x8 A2 = __builtin_bit_cast(bf16x8, a2u);

  f32x4 O[8];
#pragma unroll
  for (int i = 0; i < 8; ++i) O[i] = (f32x4){0.f, 0.f, 0.f, 0.f};
  float Lr[4] = {0.f, 0.f, 0.f, 0.f};
  float M = 0.0f;

  const int kv_s = tid >> 2, t4v = tid & 3;
  const int ks = kv_s >> 4, kld0 = (kv_s & 15) + 16*(t4v >> 1), ki0 = 4*(t4v & 1);

  // ---- prologue: stage tile 0 ----
  {
    const u16* vsrc = vT + (size_t)b*256*4096;
#pragma unroll
    for (int i = 0; i < 4; ++i) {
      int u = i*512 + tid;
      int row = u >> 3, slot = u & 7;
      int sb = (slot*16) ^ ((row & 7) << 4);
      gl2lds16((const char*)(vsrc + (size_t)row*4096) + sb, (char*)&vbuf[0][0] + u*16);
    }
    if (tid < 256) {
      float4 kvec = *reinterpret_cast<const float4*>(kT + ((size_t)b*4096 + kv_s)*16 + 4*t4v);
      float kf[4] = {kvec.x, kvec.y, kvec.z, kvec.w};
      us4 h4, l4;
#pragma unroll
      for (int di = 0; di < 4; ++di) {
        __hip_bfloat16 h = __float2bfloat16(kf[di]);
        float fh = __bfloat162float(h);
        __hip_bfloat16 lo = __float2bfloat16(kf[di] - fh);
        h4[di] = __builtin_bit_cast(u16, h);
        l4[di] = __builtin_bit_cast(u16, lo);
      }
      *reinterpret_cast<us4*>(&kfh[0][ks][kld0][ki0])    = h4;
      *reinterpret_cast<us4*>(&kfh[0][ks][kld0+32][ki0]) = h4;
      *reinterpret_cast<us4*>(&kfl[0][ks][kld0][ki0])    = l4;
      *reinterpret_cast<us4*>(&kfl[0][ks][kld0+32][ki0]) = l4;
    }
  }
  __syncthreads();
  const float mean = mean_s;

  // ---- main loop over 64 KV tiles of 64 ----
  for (int t = 0; t < 64; ++t) {
    const int cur = t & 1, nxt = cur ^ 1;
    const int kv0n = ((t + 1) & 63) * 64;

    float4 kvec;
    if (tid < 256)
      kvec = *reinterpret_cast<const float4*>(kT + ((size_t)b*4096 + kv0n + kv_s)*16 + 4*t4v);
    {
      const u16* vsrc = vT + (size_t)b*256*4096 + kv0n;
#pragma unroll
      for (int i = 0; i < 4; ++i) {
        int u = i*512 + tid;
        int row = u >> 3, slot = u & 7;
        int sb = (slot*16) ^ ((row & 7) << 4);
        gl2lds16((const char*)(vsrc + (size_t)row*4096) + sb, (char*)&vbuf[nxt][0] + u*16);
      }
    }

    // [A] scores
    f32x4 S[4];
#pragma unroll
    for (int s = 0; s < 4; ++s) {
      bf16x8 bh = __builtin_bit_cast(bf16x8, *reinterpret_cast<const us8*>(&kfh[cur][s][lane][0]));
      bf16x8 bl = __builtin_bit_cast(bf16x8, *reinterpret_cast<const us8*>(&kfl[cur][s][lane][0]));
      f32x4 acc = (f32x4){0.f, 0.f, 0.f, 0.f};
      acc = __builtin_amdgcn_mfma_f32_16x16x32_bf16(A1, bh, acc, 0, 0, 0);
      acc = __builtin_amdgcn_mfma_f32_16x16x32_bf16(A2, bl, acc, 0, 0, 0);
      S[s] = acc;
    }

    // [B] mask + deferred-max online softmax
    float pmax = -1e30f;
#pragma unroll
    for (int s = 0; s < 4; ++s)
#pragma unroll
      for (int r = 0; r < 4; ++r) {
        float v = S[s][r];
        v = (v < mean) ? 0.f : v;
        S[s][r] = v;
        pmax = fmaxf(pmax, v);
      }
    if (!__all(pmax <= M + 8.0f)) {
      float mw = pmax;
#pragma unroll
      for (int off = 1; off < 64; off <<= 1) mw = fmaxf(mw, __shfl_xor(mw, off));
      float Mn = fmaxf(M, mw);
      float sc = __expf(M - Mn);
#pragma unroll
      for (int i = 0; i < 8; ++i) {
        O[i][0] *= sc; O[i][1] *= sc; O[i][2] *= sc; O[i][3] *= sc;
      }
#pragma unroll
      for (int r = 0; r < 4; ++r) Lr[r] *= sc;
      M = Mn;
    }
    u16 pb[4][4];
#pragma unroll
    for (int s = 0; s < 4; ++s)
#pragma unroll
      for (int r = 0; r < 4; ++r) {
        float p = __expf(S[s][r] - M);
        Lr[r] += p;
        pb[s][r] = __builtin_bit_cast(u16, __float2bfloat16(p));
      }

    // [C] write P frags
    {
      const int ib = lane & 7;
      const int t1 = (lane >> 3) & 1;
#pragma unroll
      for (int s = 0; s < 4; ++s) {
        const int c2 = s >> 1;
        const int ldb = 16 * ((2*s + t1) & 3) + 4*g;
#pragma unroll
        for (int r = 0; r < 4; ++r) pfr[w][c2][ldb + r][ib] = pb[s][r];
      }
    }
    asm volatile("s_waitcnt lgkmcnt(0)" ::: "memory");
    __builtin_amdgcn_sched_barrier(0);

    // [G] PV
#pragma unroll
    for (int c2 = 0; c2 < 2; ++c2) {
      bf16x8 pa = __builtin_bit_cast(bf16x8, *reinterpret_cast<const us8*>(&pfr[w][c2][lane][0]));
#pragma unroll
      for (int ct = 0; ct < 8; ++ct) {
        int row = (wc*8 + ct)*16 + c16;
        int off = (c2*64 + g*16) ^ ((lane & 7) << 4);
        bf16x8 vb = __builtin_bit_cast(bf16x8,
            *reinterpret_cast<const us8*>((const char*)&vbuf[cur][0] + row*128 + off));
        O[ct] = __builtin_amdgcn_mfma_f32_16x16x32_bf16(pa, vb, O[ct], 0, 0, 0);
      }
    }

    // [H] K frags for next tile
    if (tid < 256) {
      float kf[4] = {kvec.x, kvec.y, kvec.z, kvec.w};
      us4 h4, l4;
#pragma unroll
      for (int di = 0; di < 4; ++di) {
        __hip_bfloat16 h = __float2bfloat16(kf[di]);
        float fh = __bfloat162float(h);
        __hip_bfloat16 lo = __float2bfloat16(kf[di] - fh);
        h4[di] = __builtin_bit_cast(u16, h);
        l4[di] = __builtin_bit_cast(u16, lo);
      }
      *reinterpret_cast<us4*>(&kfh[nxt][ks][kld0][ki0])    = h4;
      *reinterpret_cast<us4*>(&kfh[nxt][ks][kld0+32][ki0]) = h4;
      *reinterpret_cast<us4*>(&kfl[nxt][ks][kld0][ki0])    = l4;
      *reinterpret_cast<us4*>(&kfl[nxt][ks][kld0+32][ki0]) = l4;
    }

    __syncthreads();
  }

  // ---- epilogue ----
#pragma unroll
  for (int r = 0; r < 4; ++r) {
    float v = Lr[r];
#pragma unroll
    for (int off = 1; off < 16; off <<= 1) v += __shfl_xor(v, off);
    Lr[r] = v;
  }
  float inv[4];
#pragma unroll
  for (int r = 0; r < 4; ++r) inv[r] = 1.0f / Lr[r];
#pragma unroll
  for (int ct = 0; ct < 8; ++ct) {
    int c = (wc*8 + ct)*16 + c16;
    float* dst = ods + ((size_t)b*256 + c) * 4096u + row0 + 16*wq + 4*g;
    float4 o4 = make_float4(O[ct][0]*inv[0], O[ct][1]*inv[1], O[ct][2]*inv[2], O[ct][3]*inv[3]);
    *reinterpret_cast<float4*>(dst) = o4;
  }
}

// ---------------- bilinear 4x upsample + residual, 4 px/thread ----------------
__global__ __launch_bounds__(256) void k_up(const float* __restrict__ ods, const float* __restrict__ x,
                                            float* __restrict__ out) {
  unsigned idx4 = blockIdx.x * 256u + threadIdx.x;   // < 16777216
  int a  = (int)(idx4 & 63u);
  int i  = (int)((idx4 >> 6) & 255u);
  size_t bc = idx4 >> 14;

  float py = (i + 0.5f) * 0.25f - 0.5f;
  float y0f = floorf(py);
  float wy = py - y0f;
  int y0 = (int)y0f, y1 = y0 + 1;
  y0 = max(y0, 0); y1 = min(y1, 63);

  int xm1 = max(a - 1, 0), xp1 = min(a + 1, 63);

  const float* r0 = ods + bc * 4096u + y0 * 64;
  const float* r1 = ods + bc * 4096u + y1 * 64;
  float wy1 = 1.f - wy;
  float vm1 = wy1 * r0[xm1] + wy * r1[xm1];
  float v0  = wy1 * r0[a]   + wy * r1[a];
  float vp1 = wy1 * r0[xp1] + wy * r1[xp1];

  float4 xv = *reinterpret_cast<const float4*>(x + (size_t)idx4 * 4u);
  float4 o4;
  o4.x = fmaf(0.375f, vm1, 0.625f * v0) + xv.x;
  o4.y = fmaf(0.125f, vm1, 0.875f * v0) + xv.y;
  o4.z = fmaf(0.875f, v0, 0.125f * vp1) + xv.z;
  o4.w = fmaf(0.625f, v0, 0.375f * vp1) + xv.w;
  *reinterpret_cast<float4*>(out + (size_t)idx4 * 4u) = o4;
}

extern "C" void kernel_launch(void* const* d_in, const int* in_sizes, int n_in,
                              void* d_out, int out_size, void* d_ws, size_t ws_size,
                              hipStream_t stream) {
  const float* x  = (const float*)d_in[0];
  const float* Wq = (const float*)d_in[1];
  const float* bq = (const float*)d_in[2];
  const float* Wk = (const float*)d_in[3];
  const float* bk = (const float*)d_in[4];
  const float* Wv = (const float*)d_in[5];
  const float* bv = (const float*)d_in[6];
  float* out = (float*)d_out;

  char* ws = (char*)d_ws;
  float* xd32  = (float*)(ws + OFF_XD32);   // aliased by ods after k_qkv
  float* qT    = (float*)(ws + OFF_QT);
  float* kT    = (float*)(ws + OFF_KT);
  u16*   vT    = (u16*)(ws + OFF_VT);
  u16*   Wf    = (u16*)(ws + OFF_WF);
  float* Spart = (float*)(ws + OFF_SPART);
  float* ods   = xd32;

  k_prepw<<<dim3(16), dim3(256), 0, stream>>>(Wv, Wf);
  k_pool<<<dim3(16384), dim3(256), 0, stream>>>(x, xd32);
  k_qkv<<<dim3(512), dim3(512), 0, stream>>>(xd32, Wf, bv, Wq, bq, Wk, bk, qT, kT, vT, Spart);
  k_flash<<<dim3(256), dim3(512), 0, stream>>>(qT, kT, vT, Spart, bq, bk, ods);
  k_up<<<dim3(65536), dim3(256), 0, stream>>>(ods, x, out);
}